// Round 2
// baseline (690.665 us; speedup 1.0000x reference)
//
#include <hip/hip_runtime.h>
#include <hip/hip_bf16.h>
#include <math.h>

#define Dm   1024
#define Hh   16
#define Sx   2048

typedef short s16x8 __attribute__((ext_vector_type(8)));
typedef float f32x4 __attribute__((ext_vector_type(4)));
typedef unsigned short u16;
typedef u16 u16x4 __attribute__((ext_vector_type(4)));

#if defined(__has_builtin)
#  if __has_builtin(__builtin_amdgcn_cvt_pk_bf16_f32)
#    define HAVE_PKBF16 1
typedef __bf16 bfv2 __attribute__((ext_vector_type(2)));
#  endif
#  if __has_builtin(__builtin_amdgcn_exp2f)
#    define EXP2(x) __builtin_amdgcn_exp2f(x)
#  endif
#endif
#ifndef EXP2
#  define EXP2(x) exp2f(x)
#endif

// logit scale folded into k and p: dh^-0.5 * log2(e)
#define ATT_SCALE 0.1803368801111204f

__device__ __forceinline__ float wave_sum64(float v) {
#pragma unroll
    for (int o = 32; o > 0; o >>= 1) v += __shfl_xor(v, o, 64);
    return v;
}
__device__ __forceinline__ u16 f2bf(float x) {
    unsigned int u = __float_as_uint(x);
    unsigned int r = u + 0x7FFFu + ((u >> 16) & 1u);
    return (u16)(r >> 16);
}
__device__ __forceinline__ float bf2f(u16 h) {
    return __uint_as_float(((unsigned int)h) << 16);
}

// ---------------------------------------------------------------- LayerNorm -> pre-split bf16 hi|lo
__global__ __launch_bounds__(256) void ln_kernel(const float* __restrict__ x,
                                                 const float* __restrict__ g,
                                                 const float* __restrict__ b,
                                                 u16* __restrict__ out16) {
    int row = blockIdx.x;
    int tid = threadIdx.x;
    const float4* xr = (const float4*)(x + (size_t)row * Dm);
    float4 v = xr[tid];
    float s  = v.x + v.y + v.z + v.w;
    float ss = v.x * v.x + v.y * v.y + v.z * v.z + v.w * v.w;
    __shared__ float rbuf[8];
    s  = wave_sum64(s);
    ss = wave_sum64(ss);
    if ((tid & 63) == 0) { rbuf[tid >> 6] = s; rbuf[4 + (tid >> 6)] = ss; }
    __syncthreads();
    float mean = (rbuf[0] + rbuf[1] + rbuf[2] + rbuf[3]) * (1.0f / Dm);
    float msq  = (rbuf[4] + rbuf[5] + rbuf[6] + rbuf[7]) * (1.0f / Dm);
    float var  = msq - mean * mean;
    float rstd = 1.0f / sqrtf(var + 1e-5f);
    float4 gg = ((const float4*)g)[tid];
    float4 bb = ((const float4*)b)[tid];
    float o[4];
    o[0] = (v.x - mean) * rstd * gg.x + bb.x;
    o[1] = (v.y - mean) * rstd * gg.y + bb.y;
    o[2] = (v.z - mean) * rstd * gg.z + bb.z;
    o[3] = (v.w - mean) * rstd * gg.w + bb.w;
    u16x4 hi, lo;
#pragma unroll
    for (int i = 0; i < 4; i++) {
        u16 h = f2bf(o[i]);
        hi[i] = h;
        lo[i] = f2bf(o[i] - bf2f(h));
    }
    *(u16x4*)&out16[(size_t)row * 2048 + tid * 4]        = hi;
    *(u16x4*)&out16[(size_t)row * 2048 + 1024 + tid * 4] = lo;
}

// ---------------------------------------------------------------- sinusoidal PE -> pre-split bf16
__global__ __launch_bounds__(256) void pe_kernel(u16* __restrict__ pe16) {
    int idx = blockIdx.x * 256 + threadIdx.x;
    int r = idx >> 9;
    int t = idx & 511;
    double div = exp((double)(2 * t) * (-9.210340371976184 / 1024.0));
    double ang = (double)r * div;
    float sv = (float)sin(ang), cv = (float)cos(ang);
    u16 sh = f2bf(sv), chh = f2bf(cv);
    u16* row = pe16 + (size_t)r * 2048;
    row[2 * t]            = sh;
    row[2 * t + 1]        = chh;
    row[1024 + 2 * t]     = f2bf(sv - bf2f(sh));
    row[1024 + 2 * t + 1] = f2bf(cv - bf2f(chh));
}

// ---------------------------------------------------------------- weight transpose + bf16 hi/lo split
__global__ __launch_bounds__(256) void wconv_kernel(const float* __restrict__ W0,
                                                    const float* __restrict__ W1,
                                                    const float* __restrict__ W2,
                                                    const float* __restrict__ W3,
                                                    const float* __restrict__ W4,
                                                    u16* __restrict__ WT) {
    int wz = blockIdx.z;
    const float* W = (wz == 0) ? W0 : (wz == 1) ? W1 : (wz == 2) ? W2 : (wz == 3) ? W3 : W4;
    u16* T = WT + (size_t)wz * 1024 * 2048;
    __shared__ float tile[32][33];
    int n0 = blockIdx.x * 32, k0 = blockIdx.y * 32;
    int tx = threadIdx.x & 31, ty = threadIdx.x >> 5;
#pragma unroll
    for (int r = 0; r < 32; r += 8)
        tile[ty + r][tx] = W[(size_t)(k0 + ty + r) * 1024 + n0 + tx];
    __syncthreads();
#pragma unroll
    for (int r = 0; r < 32; r += 8) {
        int n = ty + r;
        float x = tile[tx][n];
        u16 h = f2bf(x);
        float rem = x - bf2f(h);
        T[(size_t)(n0 + n) * 2048 + k0 + tx]        = h;
        T[(size_t)(n0 + n) * 2048 + 1024 + k0 + tx] = f2bf(rem);
    }
}

// ---------------------------------------------------------------- bf16x3 MFMA GEMM (pre-split A and B)
// C = (A @ W + bias) * cscale
__global__ __launch_bounds__(256, 4) void gemm_bf16x3(const u16* __restrict__ A16,
                                                      const u16* __restrict__ WT,
                                                      const float* __restrict__ bias,
                                                      float cscale,
                                                      float* __restrict__ C,
                                                      u16* __restrict__ Cb, int M) {
    const int K = 1024, N = 1024;
    __shared__ __align__(16) u16 Ah[64 * 72];
    __shared__ __align__(16) u16 Bh[128 * 72];
    int tid = threadIdx.x;
    int bn = blockIdx.x * 128, bm = blockIdx.y * 64;
    int ar = tid >> 2, ac = (tid & 3) * 8;
    int br = tid >> 1, bs = (tid & 1);
    int w = tid >> 6, ln = tid & 63, g = ln >> 4, l15 = ln & 15;
    int wm = (w & 1) * 32, wn = (w >> 1) * 64;

    const u16* Ap = A16 + (size_t)(bm + ar) * 2048 + ac;
    const u16* Bp = WT + (size_t)(bn + br) * 2048 + bs * 1024;
    u16* Aw = &Ah[ar * 72 + ac];
    u16* Bw = &Bh[br * 72 + bs * 32];

    f32x4 acc[2][4] = {};
    s16x8 pah = *(const s16x8*)Ap;
    s16x8 pal = *(const s16x8*)(Ap + 1024);
    s16x8 pb0 = *(const s16x8*)Bp;
    s16x8 pb1 = *(const s16x8*)(Bp + 8);
    s16x8 pb2 = *(const s16x8*)(Bp + 16);
    s16x8 pb3 = *(const s16x8*)(Bp + 24);

    for (int k0 = 0; k0 < K; k0 += 32) {
        __syncthreads();
        *(s16x8*)Aw        = pah;
        *(s16x8*)(Aw + 32) = pal;
        *(s16x8*)Bw        = pb0;
        *(s16x8*)(Bw + 8)  = pb1;
        *(s16x8*)(Bw + 16) = pb2;
        *(s16x8*)(Bw + 24) = pb3;
        int kn = k0 + 32;
        if (kn < K) {
            pah = *(const s16x8*)(Ap + kn);
            pal = *(const s16x8*)(Ap + 1024 + kn);
            pb0 = *(const s16x8*)(Bp + kn);
            pb1 = *(const s16x8*)(Bp + kn + 8);
            pb2 = *(const s16x8*)(Bp + kn + 16);
            pb3 = *(const s16x8*)(Bp + kn + 24);
        }
        __syncthreads();
        s16x8 ah0 = *(const s16x8*)&Ah[(wm + l15) * 72 + g * 8];
        s16x8 al0 = *(const s16x8*)&Ah[(wm + l15) * 72 + 32 + g * 8];
        s16x8 ah1 = *(const s16x8*)&Ah[(wm + 16 + l15) * 72 + g * 8];
        s16x8 al1 = *(const s16x8*)&Ah[(wm + 16 + l15) * 72 + 32 + g * 8];
#pragma unroll
        for (int nt = 0; nt < 4; nt++) {
            int n = (wn + 16 * nt + l15) * 72;
            s16x8 bh = *(const s16x8*)&Bh[n + g * 8];
            s16x8 bl = *(const s16x8*)&Bh[n + 32 + g * 8];
            acc[0][nt] = __builtin_amdgcn_mfma_f32_16x16x32_bf16(ah0, bh, acc[0][nt], 0, 0, 0);
            acc[0][nt] = __builtin_amdgcn_mfma_f32_16x16x32_bf16(al0, bh, acc[0][nt], 0, 0, 0);
            acc[0][nt] = __builtin_amdgcn_mfma_f32_16x16x32_bf16(ah0, bl, acc[0][nt], 0, 0, 0);
            acc[1][nt] = __builtin_amdgcn_mfma_f32_16x16x32_bf16(ah1, bh, acc[1][nt], 0, 0, 0);
            acc[1][nt] = __builtin_amdgcn_mfma_f32_16x16x32_bf16(al1, bh, acc[1][nt], 0, 0, 0);
            acc[1][nt] = __builtin_amdgcn_mfma_f32_16x16x32_bf16(ah1, bl, acc[1][nt], 0, 0, 0);
        }
    }

    float bv[4];
#pragma unroll
    for (int nt = 0; nt < 4; nt++)
        bv[nt] = bias ? bias[bn + wn + 16 * nt + l15] : 0.0f;
#pragma unroll
    for (int mt = 0; mt < 2; mt++)
#pragma unroll
        for (int r = 0; r < 4; r++) {
            int row = bm + wm + 16 * mt + g * 4 + r;
            if (Cb) {
                u16* cp = Cb + (size_t)row * N + bn + wn + l15;
#pragma unroll
                for (int nt = 0; nt < 4; nt++)
                    cp[16 * nt] = f2bf((acc[mt][nt][r] + bv[nt]) * cscale);
            } else {
                float* cp = C + (size_t)row * N + bn + wn + l15;
#pragma unroll
                for (int nt = 0; nt < 4; nt++)
                    cp[16 * nt] = (acc[mt][nt][r] + bv[nt]) * cscale;
            }
        }
}

// ---------------------------------------------------------------- V transpose to tiled [b][h][jt][d][32]
__global__ __launch_bounds__(256) void vtrans_kernel(const u16* __restrict__ v,
                                                     u16* __restrict__ vT) {
    __shared__ u16 L[32 * 72];
    int jt = blockIdx.x, h = blockIdx.y, b = blockIdx.z;
    int tid = threadIdx.x;
    int row = tid >> 3, cc = tid & 7;
    const u16* src = v + ((size_t)(b * Sx + jt * 32 + row)) * Dm + h * 64 + cc * 8;
    *(s16x8*)&L[row * 72 + cc * 8] = *(const s16x8*)src;
    __syncthreads();
    int d = tid >> 2, jq = tid & 3;
    s16x8 o;
#pragma unroll
    for (int jj = 0; jj < 8; jj++) o[jj] = (short)L[(jq * 8 + jj) * 72 + d];
    u16* dst = vT + (((size_t)(b * 16 + h) * 64 + jt)) * 2048 + d * 32 + jq * 8;
    *(s16x8*)dst = o;
}

// ---------------------------------------------------------------- precompute u.k_j and vb.p_r (bf16 in; k/p pre-scaled)
__global__ __launch_bounds__(256) void ukvb_kernel(const u16* __restrict__ k,
                                                   const u16* __restrict__ pp,
                                                   const float* __restrict__ u,
                                                   const float* __restrict__ vb,
                                                   float* __restrict__ ukg,
                                                   float* __restrict__ vbg) {
    int jid = blockIdx.x * 256 + threadIdx.x;
    const u16* src; const float* vec; float* dst; int idx;
    if (jid < 2 * Hh * Sx) {
        int j = jid & 2047, h = (jid >> 11) & 15, b = jid >> 15;
        src = k + ((size_t)(b * Sx + j)) * Dm + h * 64;
        vec = u + h * 64; dst = ukg; idx = jid;
    } else {
        int j2 = jid - 2 * Hh * Sx;
        int r = j2 & 2047, h = j2 >> 11;
        src = pp + (size_t)r * Dm + h * 64;
        vec = vb + h * 64; dst = vbg; idx = j2;
    }
    float s = 0.0f;
#pragma unroll
    for (int c = 0; c < 8; c++) {
        s16x8 kk = *(const s16x8*)(src + c * 8);
#pragma unroll
        for (int i = 0; i < 8; i++) s += bf2f((u16)kk[i]) * vec[c * 8 + i];
    }
    dst[idx] = s;
}

// ---------------------------------------------------------------- MFMA helper
__device__ __forceinline__ f32x4 mfma16(s16x8 a, s16x8 b, f32x4 c) {
    return __builtin_amdgcn_mfma_f32_16x16x32_bf16(a, b, c, 0, 0, 0);
}

// ---------------------------------------------------------------- position window machinery
// PW fragment pack for one 32-position fill chunk: loaded early, consumed later.
struct PWF {
    s16x8 b00, b01, b10, b11;
    float vb0, vb1;
};

__device__ __forceinline__ PWF pw_load(int vstart,
                                       const u16* __restrict__ ppb,
                                       const float* __restrict__ vbb,
                                       int g, int l15) {
    int v0 = vstart + l15, v1 = v0 + 16;
    int pc0 = v0 < Sx ? v0 : v0 - Sx - 1; if (pc0 < 0) pc0 = 0; if (pc0 > Sx - 1) pc0 = Sx - 1;
    int pc1 = v1 < Sx ? v1 : v1 - Sx - 1; if (pc1 < 0) pc1 = 0; if (pc1 > Sx - 1) pc1 = Sx - 1;
    const u16* p0 = ppb + (size_t)pc0 * Dm;
    const u16* p1 = ppb + (size_t)pc1 * Dm;
    PWF f;
    f.b00 = *(const s16x8*)(p0 + g * 8);
    f.b01 = *(const s16x8*)(p0 + 32 + g * 8);
    f.b10 = *(const s16x8*)(p1 + g * 8);
    f.b11 = *(const s16x8*)(p1 + 32 + g * 8);
    f.vb0 = (v0 == Sx) ? 0.0f : vbb[pc0];
    f.vb1 = (v1 == Sx) ? 0.0f : vbb[pc1];
    return f;
}

// fills window chunk [vstart, vstart+32): skewed circular slots, physical = (logical_vr + row) % 96
__device__ __forceinline__ void pos_fill2(int vstart, int sb, const PWF& f,
                                          s16x8 aq0, s16x8 aq1, s16x8 ab0, s16x8 ab1,
                                          float* Ws, int rbase, int g, int l15) {
    f32x4 z = {0.f, 0.f, 0.f, 0.f};
    f32x4 e0, e1;
    if (vstart + 31 <= Sx) {                    // block-uniform branch
        e0 = mfma16(aq1, f.b01, mfma16(aq0, f.b00, z));
        e1 = mfma16(aq1, f.b11, mfma16(aq0, f.b10, z));
    } else if (vstart > Sx) {
        e0 = mfma16(ab1, f.b01, mfma16(ab0, f.b00, z));
        e1 = mfma16(ab1, f.b11, mfma16(ab0, f.b10, z));
    } else {                                    // mixed chunk (<= 2 per block)
        f32x4 d0 = mfma16(aq1, f.b01, mfma16(aq0, f.b00, z));
        f32x4 d1 = mfma16(aq1, f.b11, mfma16(aq0, f.b10, z));
        f32x4 f0 = mfma16(ab1, f.b01, mfma16(ab0, f.b00, z));
        f32x4 f1 = mfma16(ab1, f.b11, mfma16(ab0, f.b10, z));
        int v0 = vstart + l15, v1 = v0 + 16;
#pragma unroll
        for (int r = 0; r < 4; r++) {
            e0[r] = (v0 > Sx) ? f0[r] : d0[r];
            e1[r] = (v1 > Sx) ? f1[r] : d1[r];
        }
    }
    int v0 = vstart + l15, v1 = v0 + 16;
    int bs = sb + rbase;
#pragma unroll
    for (int r = 0; r < 4; r++) {
        int b2 = bs + r; if (b2 >= 96) b2 -= 96;
        int sl0 = b2 + l15; if (sl0 >= 96) sl0 -= 96;
        int sl1 = sl0 + 16; if (sl1 >= 96) sl1 -= 96;
        Ws[(rbase + r) * 98 + sl0] = (v0 == Sx) ? 0.0f : e0[r] + f.vb0;
        Ws[(rbase + r) * 98 + sl1] = (v1 == Sx) ? 0.0f : e1[r] + f.vb1;
    }
}

// ---------------------------------------------------------------- flash attention, barrier-free + prefetched
// Round-1 post-mortem: barrier-free direct-global loads exposed ~200cy L2 latency on the
// critical path (VALUBusy 39->22, dur 218->375). Fix: keep the wave-private barrier-free
// structure and the XCD grouping (FETCH 163MB->15MB, L2-resident), but restore latency
// hiding in registers: K frags + u.k prefetched a full iteration ahead; PW/V frags issued
// at the top of the body, consumed mid/late-body. Zero __syncthreads. LDS 30.2KB,
// VGPR capped at 128 by __launch_bounds__(256,4) -> 4 blocks/CU, grid 1024 = 1 generation.
__global__ __launch_bounds__(256, 4) void flash_kernel(const u16* __restrict__ q,
                                                       const u16* __restrict__ k,
                                                       const u16* __restrict__ vt,
                                                       const u16* __restrict__ pp,
                                                       const float* __restrict__ ukg,
                                                       const float* __restrict__ vbg,
                                                       u16* __restrict__ head16) {
    __shared__ u16 PA[64 * 40];
    __shared__ float Ws[64 * 98];

    int tid = threadIdx.x, blk = blockIdx.x;
    // XCD-grouped swizzle: the 32 'it' blocks sharing one (b,h) K/V/pp slice land on
    // one XCD (round-robin dispatch xcd = blk & 7); 4 slices/XCD ~ 4 MB = L2.
    int grp = (blk & 7) + 8 * (blk >> 8);       // 0..31  = b*16 + h
    int it  = (blk >> 3) & 31;
    int h = grp & 15, b = grp >> 4;
    int i0 = it * 64;
    int a0 = 1984 - i0;

    const u16* qb  = q  + ((size_t)b * Sx) * Dm + h * 64;
    const u16* kb  = k  + ((size_t)b * Sx) * Dm + h * 64;
    const u16* vtb = vt + ((size_t)(b * 16 + h) * 64) * 2048;
    const u16* ppb = pp + h * 64;
    const float* ukb = ukg + (size_t)(b * Hh + h) * Sx;
    const float* vbb = vbg + (size_t)h * Sx;

    int w = tid >> 6, ln = tid & 63, g = ln >> 4, l15 = ln & 15;
    int rbase = 16 * w + 4 * g;

    // Q fragments direct from global (one-time; latency irrelevant)
    int qrow = i0 + 16 * w + l15;
    const u16* qrp = qb + (size_t)qrow * Dm;
    s16x8 aq0 = *(const s16x8*)(qrp + g * 8);
    s16x8 aq1 = *(const s16x8*)(qrp + 32 + g * 8);
    s16x8 ab0 = {0, 0, 0, 0, 0, 0, 0, 0}, ab1 = ab0;
    if (qrow + 1 < Sx) {                         // row+1 frags for window-fill boundary
        ab0 = *(const s16x8*)(qrp + Dm + g * 8);
        ab1 = *(const s16x8*)(qrp + Dm + 32 + g * 8);
    }

    // prologue window fills: chunks 0,1,2 (Ws wave-private; immediate loads OK here)
    pos_fill2(a0,      0,  pw_load(a0,      ppb, vbb, g, l15), aq0, aq1, ab0, ab1, Ws, rbase, g, l15);
    pos_fill2(a0 + 32, 32, pw_load(a0 + 32, ppb, vbb, g, l15), aq0, aq1, ab0, ab1, Ws, rbase, g, l15);
    pos_fill2(a0 + 64, 64, pw_load(a0 + 64, ppb, vbb, g, l15), aq0, aq1, ab0, ab1, Ws, rbase, g, l15);

    f32x4 O[4] = {{0.f,0.f,0.f,0.f},{0.f,0.f,0.f,0.f},{0.f,0.f,0.f,0.f},{0.f,0.f,0.f,0.f}};
    float m_w = -1e30f;
    float l_i[4] = {0.f, 0.f, 0.f, 0.f};
    int wro[4];
#pragma unroll
    for (int r = 0; r < 4; r++) wro[r] = (rbase + r) * 98;
    int sb = 0;                 // fill slot base, cycles 0,32,64
    int jm = 63;                // (63 + j0) % 96
    int cw = (g >= 2) ? 16 : 0;           // PA write column swizzle
    int crd = (l15 >> 3) << 4;            // PA read column swizzle
    int pard = (16 * w + l15) * 40 + ((g * 8 + crd) & 31);

    const u16* pk0 = kb + (size_t)l15 * Dm;
    const u16* pk1 = kb + (size_t)(16 + l15) * Dm;
    const u16* pv  = vtb + l15 * 32 + g * 8;
    const float* pu = ukb + l15;

    // K + u.k prefetch for t=0 (critical path: consumed at top of body)
    s16x8 rk00 = *(const s16x8*)(pk0 + g * 8);
    s16x8 rk01 = *(const s16x8*)(pk0 + 32 + g * 8);
    s16x8 rk10 = *(const s16x8*)(pk1 + g * 8);
    s16x8 rk11 = *(const s16x8*)(pk1 + 32 + g * 8);
    float ruk0 = pu[0];
    float ruk1 = pu[16];

    for (int t = 0; t < 64; t++) {
        // ---- early issues: PW frags (used mid-body) and V frags (used at end)
        PWF fpw = pw_load(a0 + 32 * t + 64, ppb, vbb, g, l15);
        s16x8 bv0 = *(const s16x8*)(pv);
        s16x8 bv1 = *(const s16x8*)(pv + 512);
        s16x8 bv2 = *(const s16x8*)(pv + 1024);
        s16x8 bv3 = *(const s16x8*)(pv + 1536);
        pv += 2048;

        // ---- next-iteration K + u.k prefetch (over-run at t=63 stays in workspace)
        const u16* npk0 = pk0 + 32 * Dm;
        const u16* npk1 = pk1 + 32 * Dm;
        s16x8 nk00 = *(const s16x8*)(npk0 + g * 8);
        s16x8 nk01 = *(const s16x8*)(npk0 + 32 + g * 8);
        s16x8 nk10 = *(const s16x8*)(npk1 + g * 8);
        s16x8 nk11 = *(const s16x8*)(npk1 + 32 + g * 8);
        float nuk0 = pu[32];
        float nuk1 = pu[48];

        // ---- content scores with current-iteration K (already resident)
        f32x4 z = {0.f, 0.f, 0.f, 0.f};
        f32x4 s0 = mfma16(aq1, rk01, mfma16(aq0, rk00, z));
        f32x4 s1 = mfma16(aq1, rk11, mfma16(aq0, rk10, z));

        // ---- window fill for logical vr in [j0+64, j0+96)  (chunk t+2)
        if (t >= 1) {
            pos_fill2(a0 + 32 * t + 64, sb, fpw, aq0, aq1, ab0, ab1, Ws, rbase, g, l15);
            sb += 32; if (sb >= 96) sb -= 96;
        }

        // ---- combine + online softmax; skewed read slots are row-independent
        int si0 = jm + l15; if (si0 >= 96) si0 -= 96;
        int si1 = si0 + 16; if (si1 >= 96) si1 -= 96;
        jm += 32; if (jm >= 96) jm -= 96;
        float lg0[4], lg1[4];
#pragma unroll
        for (int r = 0; r < 4; r++) {
            lg0[r] = s0[r] + ruk0 + Ws[wro[r] + si0];
            lg1[r] = s1[r] + ruk1 + Ws[wro[r] + si1];
        }
        float pmax = fmaxf(fmaxf(fmaxf(lg0[0], lg1[0]), fmaxf(lg0[1], lg1[1])),
                           fmaxf(fmaxf(lg0[2], lg1[2]), fmaxf(lg0[3], lg1[3])));
        // threshold-deferred max: any upper bound keeps the math exact (P <= 2^8,
        // fine in f32 accum and bf16 P). Full 6-shfl reduce only on rare trigger.
        if (__any(pmax > m_w + 8.0f)) {
            float mx = pmax;
#pragma unroll
            for (int o = 1; o < 64; o <<= 1) mx = fmaxf(mx, __shfl_xor(mx, o, 64));
            float alpha = EXP2(m_w - mx);
            m_w = mx;
            l_i[0] *= alpha; l_i[1] *= alpha; l_i[2] *= alpha; l_i[3] *= alpha;
#pragma unroll
            for (int nt = 0; nt < 4; nt++)
#pragma unroll
                for (int r = 0; r < 4; r++) O[nt][r] *= alpha;
        }
        int c0 = l15 + cw;
        int c1 = l15 + 16 - cw;
#pragma unroll
        for (int r = 0; r < 4; r++) {
            float e0v = EXP2(lg0[r] - m_w);
            float e1v = EXP2(lg1[r] - m_w);
            l_i[r] += e0v + e1v;
#ifdef HAVE_PKBF16
            bfv2 pk2 = __builtin_amdgcn_cvt_pk_bf16_f32(e0v, e1v);
            PA[(rbase + r) * 40 + c0] = __builtin_bit_cast(u16, pk2[0]);
            PA[(rbase + r) * 40 + c1] = __builtin_bit_cast(u16, pk2[1]);
#else
            PA[(rbase + r) * 40 + c0] = f2bf(e0v);
            PA[(rbase + r) * 40 + c1] = f2bf(e1v);
#endif
        }

        // ---- O += P.V (PA wave-private; DS ops in-order within a wave)
        {
            s16x8 ap = *(const s16x8*)&PA[pard];
            O[0] = mfma16(ap, bv0, O[0]);
            O[1] = mfma16(ap, bv1, O[1]);
            O[2] = mfma16(ap, bv2, O[2]);
            O[3] = mfma16(ap, bv3, O[3]);
        }

        // ---- rotate prefetched K
        rk00 = nk00; rk01 = nk01; rk10 = nk10; rk11 = nk11;
        ruk0 = nuk0; ruk1 = nuk1;
        pk0 = npk0; pk1 = npk1;
        pu += 32;
    }

    // epilogue: cross-lane l sum, write pre-split bf16 head
#pragma unroll
    for (int r = 0; r < 4; r++) {
        float l = l_i[r];
#pragma unroll
        for (int o = 1; o < 16; o <<= 1) l += __shfl_xor(l, o, 64);
        float inv = 1.0f / l;
        int grow = i0 + rbase + r;
        u16* dst = head16 + (size_t)(b * Sx + grow) * 2048 + h * 64 + l15;
#pragma unroll
        for (int nt = 0; nt < 4; nt++) {
            float f = O[nt][r] * inv;
            u16 hh = f2bf(f);
            dst[16 * nt]        = hh;
            dst[1024 + 16 * nt] = f2bf(f - bf2f(hh));
        }
    }
}

// ---------------------------------------------------------------- launcher
extern "C" void kernel_launch(void* const* d_in, const int* in_sizes, int n_in,
                              void* d_out, int out_size, void* d_ws, size_t ws_size,
                              hipStream_t stream) {
    const float* x    = (const float*)d_in[0];
    const float* ln_g = (const float*)d_in[1];
    const float* ln_b = (const float*)d_in[2];
    const float* Wq   = (const float*)d_in[3];
    const float* bq   = (const float*)d_in[4];
    const float* Wk   = (const float*)d_in[5];
    const float* bk   = (const float*)d_in[6];
    const float* Wv   = (const float*)d_in[7];
    const float* bv   = (const float*)d_in[8];
    const float* Wp   = (const float*)d_in[9];
    const float* Wo   = (const float*)d_in[10];
    const float* bo   = (const float*)d_in[11];
    const float* ub   = (const float*)d_in[12];
    const float* vbias= (const float*)d_in[13];

    float* out = (float*)d_out;
    u16* base  = (u16*)d_ws;

    const int MROWS = 2 * Sx;                          // 4096
    u16* xn16   = base;                                // [4096][2048] hi|lo
    u16* head16 = base + 8u  * 1024 * 1024;            // [4096][2048] hi|lo
    u16* pe16   = base + 16u * 1024 * 1024;            // [2048][2048] hi|lo
    u16* qb16   = base + 20u * 1024 * 1024;            // [4096][1024]
    u16* kb16   = base + 24u * 1024 * 1024;
    u16* vb16   = base + 28u * 1024 * 1024;
    u16* pp16   = base + 32u * 1024 * 1024;            // [2048][1024]
    u16* vT16   = base + 34u * 1024 * 1024;            // [2][16][64][64][32]
    u16* WT     = base + 38u * 1024 * 1024;            // 5 x [1024][2048]
    float* ukg  = (float*)(base + 48u * 1024 * 1024);
    float* vbg  = ukg + 2 * Hh * Sx;

    ln_kernel<<<MROWS, 256, 0, stream>>>(x, ln_g, ln_b, xn16);
    pe_kernel<<<Sx * 512 / 256, 256, 0, stream>>>(pe16);

    dim3 gw(32, 32, 5);
    wconv_kernel<<<gw, 256, 0, stream>>>(Wq, Wk, Wv, Wp, Wo, WT);

    dim3 g1(8, MROWS / 64);
    dim3 g2(8, Sx / 64);
    gemm_bf16x3<<<g1, 256, 0, stream>>>(xn16, WT + 0u * 1024 * 2048, bq, 1.0f,      nullptr, qb16, MROWS);
    gemm_bf16x3<<<g1, 256, 0, stream>>>(xn16, WT + 1u * 1024 * 2048, bk, ATT_SCALE, nullptr, kb16, MROWS);
    gemm_bf16x3<<<g1, 256, 0, stream>>>(xn16, WT + 2u * 1024 * 2048, bv, 1.0f,      nullptr, vb16, MROWS);
    gemm_bf16x3<<<g2, 256, 0, stream>>>(pe16, WT + 3u * 1024 * 2048, nullptr, ATT_SCALE, nullptr, pp16, Sx);

    dim3 gv(Sx / 32, Hh, 2);
    vtrans_kernel<<<gv, 256, 0, stream>>>(vb16, vT16);

    ukvb_kernel<<<(2 * Hh * Sx + Hh * Sx) / 256, 256, 0, stream>>>(kb16, pp16, ub, vbias, ukg, vbg);

    flash_kernel<<<2 * Hh * 32, 256, 0, stream>>>(qb16, kb16, vT16, pp16, ukg, vbg, head16);

    gemm_bf16x3<<<g1, 256, 0, stream>>>(head16, WT + 4u * 1024 * 2048, bo, 1.0f, out, nullptr, MROWS);
}

// Round 3
// 454.191 us; speedup vs baseline: 1.5206x; 1.5206x over previous
//
#include <hip/hip_runtime.h>
#include <hip/hip_bf16.h>
#include <math.h>

#define Dm   1024
#define Hh   16
#define Sx   2048

typedef short s16x8 __attribute__((ext_vector_type(8)));
typedef float f32x4 __attribute__((ext_vector_type(4)));
typedef unsigned short u16;
typedef u16 u16x4 __attribute__((ext_vector_type(4)));

#if defined(__has_builtin)
#  if __has_builtin(__builtin_amdgcn_cvt_pk_bf16_f32)
#    define HAVE_PKBF16 1
typedef __bf16 bfv2 __attribute__((ext_vector_type(2)));
#  endif
#  if __has_builtin(__builtin_amdgcn_exp2f)
#    define EXP2(x) __builtin_amdgcn_exp2f(x)
#  endif
#endif
#ifndef EXP2
#  define EXP2(x) exp2f(x)
#endif

// logit scale folded into k and p: dh^-0.5 * log2(e)
#define ATT_SCALE 0.1803368801111204f

__device__ __forceinline__ float wave_sum64(float v) {
#pragma unroll
    for (int o = 32; o > 0; o >>= 1) v += __shfl_xor(v, o, 64);
    return v;
}
__device__ __forceinline__ u16 f2bf(float x) {
    unsigned int u = __float_as_uint(x);
    unsigned int r = u + 0x7FFFu + ((u >> 16) & 1u);
    return (u16)(r >> 16);
}
__device__ __forceinline__ float bf2f(u16 h) {
    return __uint_as_float(((unsigned int)h) << 16);
}

// ---------------------------------------------------------------- LayerNorm -> pre-split bf16 hi|lo
__global__ __launch_bounds__(256) void ln_kernel(const float* __restrict__ x,
                                                 const float* __restrict__ g,
                                                 const float* __restrict__ b,
                                                 u16* __restrict__ out16) {
    int row = blockIdx.x;
    int tid = threadIdx.x;
    const float4* xr = (const float4*)(x + (size_t)row * Dm);
    float4 v = xr[tid];
    float s  = v.x + v.y + v.z + v.w;
    float ss = v.x * v.x + v.y * v.y + v.z * v.z + v.w * v.w;
    __shared__ float rbuf[8];
    s  = wave_sum64(s);
    ss = wave_sum64(ss);
    if ((tid & 63) == 0) { rbuf[tid >> 6] = s; rbuf[4 + (tid >> 6)] = ss; }
    __syncthreads();
    float mean = (rbuf[0] + rbuf[1] + rbuf[2] + rbuf[3]) * (1.0f / Dm);
    float msq  = (rbuf[4] + rbuf[5] + rbuf[6] + rbuf[7]) * (1.0f / Dm);
    float var  = msq - mean * mean;
    float rstd = 1.0f / sqrtf(var + 1e-5f);
    float4 gg = ((const float4*)g)[tid];
    float4 bb = ((const float4*)b)[tid];
    float o[4];
    o[0] = (v.x - mean) * rstd * gg.x + bb.x;
    o[1] = (v.y - mean) * rstd * gg.y + bb.y;
    o[2] = (v.z - mean) * rstd * gg.z + bb.z;
    o[3] = (v.w - mean) * rstd * gg.w + bb.w;
    u16x4 hi, lo;
#pragma unroll
    for (int i = 0; i < 4; i++) {
        u16 h = f2bf(o[i]);
        hi[i] = h;
        lo[i] = f2bf(o[i] - bf2f(h));
    }
    *(u16x4*)&out16[(size_t)row * 2048 + tid * 4]        = hi;
    *(u16x4*)&out16[(size_t)row * 2048 + 1024 + tid * 4] = lo;
}

// ---------------------------------------------------------------- sinusoidal PE -> pre-split bf16
__global__ __launch_bounds__(256) void pe_kernel(u16* __restrict__ pe16) {
    int idx = blockIdx.x * 256 + threadIdx.x;
    int r = idx >> 9;
    int t = idx & 511;
    double div = exp((double)(2 * t) * (-9.210340371976184 / 1024.0));
    double ang = (double)r * div;
    float sv = (float)sin(ang), cv = (float)cos(ang);
    u16 sh = f2bf(sv), chh = f2bf(cv);
    u16* row = pe16 + (size_t)r * 2048;
    row[2 * t]            = sh;
    row[2 * t + 1]        = chh;
    row[1024 + 2 * t]     = f2bf(sv - bf2f(sh));
    row[1024 + 2 * t + 1] = f2bf(cv - bf2f(chh));
}

// ---------------------------------------------------------------- weight transpose + bf16 hi/lo split
__global__ __launch_bounds__(256) void wconv_kernel(const float* __restrict__ W0,
                                                    const float* __restrict__ W1,
                                                    const float* __restrict__ W2,
                                                    const float* __restrict__ W3,
                                                    const float* __restrict__ W4,
                                                    u16* __restrict__ WT) {
    int wz = blockIdx.z;
    const float* W = (wz == 0) ? W0 : (wz == 1) ? W1 : (wz == 2) ? W2 : (wz == 3) ? W3 : W4;
    u16* T = WT + (size_t)wz * 1024 * 2048;
    __shared__ float tile[32][33];
    int n0 = blockIdx.x * 32, k0 = blockIdx.y * 32;
    int tx = threadIdx.x & 31, ty = threadIdx.x >> 5;
#pragma unroll
    for (int r = 0; r < 32; r += 8)
        tile[ty + r][tx] = W[(size_t)(k0 + ty + r) * 1024 + n0 + tx];
    __syncthreads();
#pragma unroll
    for (int r = 0; r < 32; r += 8) {
        int n = ty + r;
        float x = tile[tx][n];
        u16 h = f2bf(x);
        float rem = x - bf2f(h);
        T[(size_t)(n0 + n) * 2048 + k0 + tx]        = h;
        T[(size_t)(n0 + n) * 2048 + 1024 + k0 + tx] = f2bf(rem);
    }
}

// ---------------------------------------------------------------- bf16x3 MFMA GEMM (pre-split A and B)
// C = (A @ W + bias) * cscale
__global__ __launch_bounds__(256, 4) void gemm_bf16x3(const u16* __restrict__ A16,
                                                      const u16* __restrict__ WT,
                                                      const float* __restrict__ bias,
                                                      float cscale,
                                                      float* __restrict__ C,
                                                      u16* __restrict__ Cb, int M) {
    const int K = 1024, N = 1024;
    __shared__ __align__(16) u16 Ah[64 * 72];
    __shared__ __align__(16) u16 Bh[128 * 72];
    int tid = threadIdx.x;
    int bn = blockIdx.x * 128, bm = blockIdx.y * 64;
    int ar = tid >> 2, ac = (tid & 3) * 8;
    int br = tid >> 1, bs = (tid & 1);
    int w = tid >> 6, ln = tid & 63, g = ln >> 4, l15 = ln & 15;
    int wm = (w & 1) * 32, wn = (w >> 1) * 64;

    const u16* Ap = A16 + (size_t)(bm + ar) * 2048 + ac;
    const u16* Bp = WT + (size_t)(bn + br) * 2048 + bs * 1024;
    u16* Aw = &Ah[ar * 72 + ac];
    u16* Bw = &Bh[br * 72 + bs * 32];

    f32x4 acc[2][4] = {};
    s16x8 pah = *(const s16x8*)Ap;
    s16x8 pal = *(const s16x8*)(Ap + 1024);
    s16x8 pb0 = *(const s16x8*)Bp;
    s16x8 pb1 = *(const s16x8*)(Bp + 8);
    s16x8 pb2 = *(const s16x8*)(Bp + 16);
    s16x8 pb3 = *(const s16x8*)(Bp + 24);

    for (int k0 = 0; k0 < K; k0 += 32) {
        __syncthreads();
        *(s16x8*)Aw        = pah;
        *(s16x8*)(Aw + 32) = pal;
        *(s16x8*)Bw        = pb0;
        *(s16x8*)(Bw + 8)  = pb1;
        *(s16x8*)(Bw + 16) = pb2;
        *(s16x8*)(Bw + 24) = pb3;
        int kn = k0 + 32;
        if (kn < K) {
            pah = *(const s16x8*)(Ap + kn);
            pal = *(const s16x8*)(Ap + 1024 + kn);
            pb0 = *(const s16x8*)(Bp + kn);
            pb1 = *(const s16x8*)(Bp + kn + 8);
            pb2 = *(const s16x8*)(Bp + kn + 16);
            pb3 = *(const s16x8*)(Bp + kn + 24);
        }
        __syncthreads();
        s16x8 ah0 = *(const s16x8*)&Ah[(wm + l15) * 72 + g * 8];
        s16x8 al0 = *(const s16x8*)&Ah[(wm + l15) * 72 + 32 + g * 8];
        s16x8 ah1 = *(const s16x8*)&Ah[(wm + 16 + l15) * 72 + g * 8];
        s16x8 al1 = *(const s16x8*)&Ah[(wm + 16 + l15) * 72 + 32 + g * 8];
#pragma unroll
        for (int nt = 0; nt < 4; nt++) {
            int n = (wn + 16 * nt + l15) * 72;
            s16x8 bh = *(const s16x8*)&Bh[n + g * 8];
            s16x8 bl = *(const s16x8*)&Bh[n + 32 + g * 8];
            acc[0][nt] = __builtin_amdgcn_mfma_f32_16x16x32_bf16(ah0, bh, acc[0][nt], 0, 0, 0);
            acc[0][nt] = __builtin_amdgcn_mfma_f32_16x16x32_bf16(al0, bh, acc[0][nt], 0, 0, 0);
            acc[0][nt] = __builtin_amdgcn_mfma_f32_16x16x32_bf16(ah0, bl, acc[0][nt], 0, 0, 0);
            acc[1][nt] = __builtin_amdgcn_mfma_f32_16x16x32_bf16(ah1, bh, acc[1][nt], 0, 0, 0);
            acc[1][nt] = __builtin_amdgcn_mfma_f32_16x16x32_bf16(al1, bh, acc[1][nt], 0, 0, 0);
            acc[1][nt] = __builtin_amdgcn_mfma_f32_16x16x32_bf16(ah1, bl, acc[1][nt], 0, 0, 0);
        }
    }

    float bv[4];
#pragma unroll
    for (int nt = 0; nt < 4; nt++)
        bv[nt] = bias ? bias[bn + wn + 16 * nt + l15] : 0.0f;
#pragma unroll
    for (int mt = 0; mt < 2; mt++)
#pragma unroll
        for (int r = 0; r < 4; r++) {
            int row = bm + wm + 16 * mt + g * 4 + r;
            if (Cb) {
                u16* cp = Cb + (size_t)row * N + bn + wn + l15;
#pragma unroll
                for (int nt = 0; nt < 4; nt++)
                    cp[16 * nt] = f2bf((acc[mt][nt][r] + bv[nt]) * cscale);
            } else {
                float* cp = C + (size_t)row * N + bn + wn + l15;
#pragma unroll
                for (int nt = 0; nt < 4; nt++)
                    cp[16 * nt] = (acc[mt][nt][r] + bv[nt]) * cscale;
            }
        }
}

// ---------------------------------------------------------------- V transpose to tiled [b][h][jt][d][32]
__global__ __launch_bounds__(256) void vtrans_kernel(const u16* __restrict__ v,
                                                     u16* __restrict__ vT) {
    __shared__ u16 L[32 * 72];
    int jt = blockIdx.x, h = blockIdx.y, b = blockIdx.z;
    int tid = threadIdx.x;
    int row = tid >> 3, cc = tid & 7;
    const u16* src = v + ((size_t)(b * Sx + jt * 32 + row)) * Dm + h * 64 + cc * 8;
    *(s16x8*)&L[row * 72 + cc * 8] = *(const s16x8*)src;
    __syncthreads();
    int d = tid >> 2, jq = tid & 3;
    s16x8 o;
#pragma unroll
    for (int jj = 0; jj < 8; jj++) o[jj] = (short)L[(jq * 8 + jj) * 72 + d];
    u16* dst = vT + (((size_t)(b * 16 + h) * 64 + jt)) * 2048 + d * 32 + jq * 8;
    *(s16x8*)dst = o;
}

// ---------------------------------------------------------------- precompute u.k_j and vb.p_r (bf16 in; k/p pre-scaled)
__global__ __launch_bounds__(256) void ukvb_kernel(const u16* __restrict__ k,
                                                   const u16* __restrict__ pp,
                                                   const float* __restrict__ u,
                                                   const float* __restrict__ vb,
                                                   float* __restrict__ ukg,
                                                   float* __restrict__ vbg) {
    int jid = blockIdx.x * 256 + threadIdx.x;
    const u16* src; const float* vec; float* dst; int idx;
    if (jid < 2 * Hh * Sx) {
        int j = jid & 2047, h = (jid >> 11) & 15, b = jid >> 15;
        src = k + ((size_t)(b * Sx + j)) * Dm + h * 64;
        vec = u + h * 64; dst = ukg; idx = jid;
    } else {
        int j2 = jid - 2 * Hh * Sx;
        int r = j2 & 2047, h = j2 >> 11;
        src = pp + (size_t)r * Dm + h * 64;
        vec = vb + h * 64; dst = vbg; idx = j2;
    }
    float s = 0.0f;
#pragma unroll
    for (int c = 0; c < 8; c++) {
        s16x8 kk = *(const s16x8*)(src + c * 8);
#pragma unroll
        for (int i = 0; i < 8; i++) s += bf2f((u16)kk[i]) * vec[c * 8 + i];
    }
    dst[idx] = s;
}

// ---------------------------------------------------------------- MFMA helpers for flash
__device__ __forceinline__ void wfill2(s16x8 a0, s16x8 a1, const u16* PW,
                                       int g, int l15, f32x4& d0, f32x4& d1) {
    f32x4 z = {0.f, 0.f, 0.f, 0.f};
    s16x8 b00 = *(const s16x8*)&PW[l15 * 72 + g * 8];
    s16x8 b01 = *(const s16x8*)&PW[l15 * 72 + 32 + g * 8];
    s16x8 b10 = *(const s16x8*)&PW[(16 + l15) * 72 + g * 8];
    s16x8 b11 = *(const s16x8*)&PW[(16 + l15) * 72 + 32 + g * 8];
    d0 = __builtin_amdgcn_mfma_f32_16x16x32_bf16(a0, b00, z, 0, 0, 0);
    d0 = __builtin_amdgcn_mfma_f32_16x16x32_bf16(a1, b01, d0, 0, 0, 0);
    d1 = __builtin_amdgcn_mfma_f32_16x16x32_bf16(a0, b10, z, 0, 0, 0);
    d1 = __builtin_amdgcn_mfma_f32_16x16x32_bf16(a1, b11, d1, 0, 0, 0);
}

// fill window chunk: skewed circular slots, physical = (logical_vr + row) % 96, stride 98
__device__ __forceinline__ void window_fill(s16x8 aq0, s16x8 aq1, s16x8 ab0, s16x8 ab1,
                                            const u16* PW, float* Ws,
                                            const float* __restrict__ vbb,
                                            int vstart, int sb, int rbase, int g, int l15) {
    f32x4 e0, e1;
    if (vstart + 31 <= Sx) {
        wfill2(aq0, aq1, PW, g, l15, e0, e1);
    } else if (vstart > Sx) {
        wfill2(ab0, ab1, PW, g, l15, e0, e1);
    } else {
        f32x4 d0, d1, f0, f1;
        wfill2(aq0, aq1, PW, g, l15, d0, d1);
        wfill2(ab0, ab1, PW, g, l15, f0, f1);
        int v0 = vstart + l15, v1 = vstart + 16 + l15;
#pragma unroll
        for (int r = 0; r < 4; r++) {
            e0[r] = (v0 > Sx) ? f0[r] : d0[r];
            e1[r] = (v1 > Sx) ? f1[r] : d1[r];
        }
    }
    int v0 = vstart + l15, v1 = vstart + 16 + l15;
    int pc0 = v0 < Sx ? v0 : v0 - Sx - 1;
    int pc1 = v1 < Sx ? v1 : v1 - Sx - 1;
    float vb0 = (v0 == Sx) ? 0.0f : vbb[pc0];
    float vb1 = (v1 == Sx) ? 0.0f : vbb[pc1];
    int bs = sb + rbase;
#pragma unroll
    for (int r = 0; r < 4; r++) {
        int b2 = bs + r; if (b2 >= 96) b2 -= 96;
        int sl0 = b2 + l15; if (sl0 >= 96) sl0 -= 96;
        int sl1 = sl0 + 16; if (sl1 >= 96) sl1 -= 96;
        Ws[(rbase + r) * 98 + sl0] = (v0 == Sx) ? 0.0f : e0[r] + vb0;
        Ws[(rbase + r) * 98 + sl1] = (v1 == Sx) ? 0.0f : e1[r] + vb1;
    }
}

// ---------------------------------------------------------------- flash attention
// Round-0 structure (LDS-staged K/PW, 2 barriers/iter, reg-prefetch) + occupancy package:
//   * Qs aliased over Ws (Qs is prologue-only after fragment hoist)  -9.4 KB
//   * V staging dropped: coalesced direct-global bv loads, issued early  -4 KB
//   * LDS 53 -> 38.5 KB => 4 blocks/CU; grid 1024 = exactly 1 resident generation
//   * XCD-grouped block swizzle (rounds 1-2: FETCH 163 MB -> 15 MB, L2-resident)
//   * deferred wave-max (__any, threshold 8) -- harness-verified exact in r1/r2
__global__ __launch_bounds__(256, 4) void flash_kernel(const u16* __restrict__ q,
                                                       const u16* __restrict__ k,
                                                       const u16* __restrict__ vt,
                                                       const u16* __restrict__ pp,
                                                       const float* __restrict__ ukg,
                                                       const float* __restrict__ vbg,
                                                       u16* __restrict__ head16) {
    __shared__ __align__(16) unsigned char smem[39424];
    float* Ws = (float*)smem;                    // 64*98*4 = 25088 (live whole kernel)
    u16*   Qs = (u16*)smem;                      // 65*72*2 = 9360  (prologue only, aliased)
    u16*   Kt = (u16*)(smem + 25088);            // 32*72*2 = 4608
    u16*   PW = (u16*)(smem + 29696);            // 32*72*2 = 4608
    u16*   PA = (u16*)(smem + 34304);            // 64*40*2 = 5120

    int tid = threadIdx.x, blk = blockIdx.x;
    // XCD-grouped swizzle: with round-robin dispatch (xcd = blk & 7) each XCD hosts
    // 4 (b,h) groups x 32 it-tiles; working set ~2.5 MB < 4 MB L2 per XCD.
    int grp = (blk & 7) + 8 * (blk >> 8);        // 0..31 = b*16 + h
    int it  = (blk >> 3) & 31;
    int h = grp & 15, b = grp >> 4;
    int i0 = it * 64;
    int a0 = 1984 - i0;

    const u16* qb  = q  + ((size_t)b * Sx) * Dm + h * 64;
    const u16* kb  = k  + ((size_t)b * Sx) * Dm + h * 64;
    const u16* vtb = vt + ((size_t)(b * 16 + h) * 64) * 2048;
    const u16* ppb = pp + h * 64;
    const float* ukb = ukg + (size_t)(b * Hh + h) * Sx;
    const float* vbb = vbg + (size_t)h * Sx;

    int w = tid >> 6, ln = tid & 63, g = ln >> 4, l15 = ln & 15;
    int rv = tid >> 3, ch = tid & 7;
    int rbase = 16 * w + 4 * g;

    // stage Q (65 bf16 rows) into the region later reused as Ws
    for (int c = tid; c < 65 * 8; c += 256) {
        int row = c >> 3, cc = c & 7;
        int i = i0 + row;
        s16x8 tv = {0, 0, 0, 0, 0, 0, 0, 0};
        if (i < Sx) tv = *(const s16x8*)(qb + (size_t)i * Dm + cc * 8);
        *(s16x8*)&Qs[row * 72 + cc * 8] = tv;
    }
    __syncthreads();

    // hoisted, loop-invariant A fragments (QK row and row+1 for window fill)
    s16x8 aq0 = *(const s16x8*)&Qs[(16 * w + l15) * 72 + g * 8];
    s16x8 aq1 = *(const s16x8*)&Qs[(16 * w + l15) * 72 + 32 + g * 8];
    s16x8 ab0 = *(const s16x8*)&Qs[(16 * w + 1 + l15) * 72 + g * 8];
    s16x8 ab1 = *(const s16x8*)&Qs[(16 * w + 1 + l15) * 72 + 32 + g * 8];
    __syncthreads();     // all waves done reading Qs before any Ws write (aliased)

    // prologue window fills: logical vrb = 0, 32, 64
    for (int f = 0; f < 3; f++) {
        int vrb = f * 32;
        if (f) __syncthreads();
        {
            int vv = a0 + vrb + rv;
            s16x8 tv = {0, 0, 0, 0, 0, 0, 0, 0};
            if (vv != Sx) {
                int pc = vv < Sx ? vv : vv - Sx - 1;
                tv = *(const s16x8*)(ppb + (size_t)pc * Dm + ch * 8);
            }
            *(s16x8*)&PW[rv * 72 + ch * 8] = tv;
        }
        __syncthreads();
        window_fill(aq0, aq1, ab0, ab1, PW, Ws, vbb, a0 + vrb, vrb, rbase, g, l15);
    }

    f32x4 O[4] = {{0.f,0.f,0.f,0.f},{0.f,0.f,0.f,0.f},{0.f,0.f,0.f,0.f},{0.f,0.f,0.f,0.f}};
    float m_w = -1e30f;
    float l_i[4] = {0.f, 0.f, 0.f, 0.f};
    int wro[4];
#pragma unroll
    for (int r = 0; r < 4; r++) wro[r] = (rbase + r) * 98;
    int sb = 0;                 // fill slot base, cycles 0,32,64
    int jm = 63;                // (63 + j0) % 96
    int cw = (g >= 2) ? 16 : 0;           // PA write column swizzle
    int crd = (l15 >> 3) << 4;            // PA read column swizzle
    int pard = (16 * w + l15) * 40 + ((g * 8 + crd) & 31);

    // incremental prefetch pointers (over-run at t=63 stays inside workspace)
    const u16* pK = kb + (size_t)rv * Dm + ch * 8;
    const u16* pV = vtb + l15 * 32 + g * 8;    // coalesced 1KB/wave direct V reads
    s16x8 rK = *(const s16x8*)pK;
    s16x8 rPW = {0, 0, 0, 0, 0, 0, 0, 0};

    for (int t = 0; t < 64; t++) {
        int j0 = t * 32;
        __syncthreads();   // B0
        *(s16x8*)&Kt[rv * 72 + ch * 8] = rK;
        if (t >= 1) *(s16x8*)&PW[rv * 72 + ch * 8] = rPW;

        // V fragments: direct-global early issue, consumed at end of body
        s16x8 bv0 = *(const s16x8*)(pV);
        s16x8 bv1 = *(const s16x8*)(pV + 512);
        s16x8 bv2 = *(const s16x8*)(pV + 1024);
        s16x8 bv3 = *(const s16x8*)(pV + 1536);
        pV += 2048;

        pK += 32 * Dm;
        rK = *(const s16x8*)pK;
        {
            int vv = a0 + (t + 3) * 32 + rv;
            s16x8 z8 = {0, 0, 0, 0, 0, 0, 0, 0};
            if (vv != Sx) {
                int pc = vv < Sx ? vv : vv - Sx - 1;
                if (pc > Sx - 1) pc = Sx - 1;
                z8 = *(const s16x8*)(ppb + (size_t)pc * Dm + ch * 8);
            }
            rPW = z8;
        }
        float uk0 = ukb[j0 + l15];
        float uk1 = ukb[j0 + 16 + l15];
        __syncthreads();   // B1

        // ---- content scores (pre-scaled k)
        f32x4 s0, s1;
        {
            f32x4 z = {0.f, 0.f, 0.f, 0.f};
            s16x8 bk00 = *(const s16x8*)&Kt[l15 * 72 + g * 8];
            s16x8 bk01 = *(const s16x8*)&Kt[l15 * 72 + 32 + g * 8];
            s16x8 bk10 = *(const s16x8*)&Kt[(16 + l15) * 72 + g * 8];
            s16x8 bk11 = *(const s16x8*)&Kt[(16 + l15) * 72 + 32 + g * 8];
            s0 = __builtin_amdgcn_mfma_f32_16x16x32_bf16(aq0, bk00, z, 0, 0, 0);
            s0 = __builtin_amdgcn_mfma_f32_16x16x32_bf16(aq1, bk01, s0, 0, 0, 0);
            s1 = __builtin_amdgcn_mfma_f32_16x16x32_bf16(aq0, bk10, z, 0, 0, 0);
            s1 = __builtin_amdgcn_mfma_f32_16x16x32_bf16(aq1, bk11, s1, 0, 0, 0);
        }

        // ---- window fill for logical vr in [j0+64, j0+96)
        if (t >= 1) {
            window_fill(aq0, aq1, ab0, ab1, PW, Ws, vbb, a0 + j0 + 64, sb, rbase, g, l15);
            sb += 32; if (sb >= 96) sb -= 96;
        }

        // ---- combine + online softmax; skewed read slots are row-independent
        int si0 = jm + l15; if (si0 >= 96) si0 -= 96;
        int si1 = si0 + 16; if (si1 >= 96) si1 -= 96;
        jm += 32; if (jm >= 96) jm -= 96;
        float lg0[4], lg1[4];
#pragma unroll
        for (int r = 0; r < 4; r++) {
            lg0[r] = s0[r] + uk0 + Ws[wro[r] + si0];
            lg1[r] = s1[r] + uk1 + Ws[wro[r] + si1];
        }
        float pmax = fmaxf(fmaxf(fmaxf(lg0[0], lg1[0]), fmaxf(lg0[1], lg1[1])),
                           fmaxf(fmaxf(lg0[2], lg1[2]), fmaxf(lg0[3], lg1[3])));
        // threshold-deferred max (exact: any upper bound works; P <= 2^8 fine in f32/bf16)
        if (__any(pmax > m_w + 8.0f)) {
            float mx = pmax;
#pragma unroll
            for (int o = 1; o < 64; o <<= 1) mx = fmaxf(mx, __shfl_xor(mx, o, 64));
            float alpha = EXP2(m_w - mx);
            m_w = mx;
            l_i[0] *= alpha; l_i[1] *= alpha; l_i[2] *= alpha; l_i[3] *= alpha;
#pragma unroll
            for (int nt = 0; nt < 4; nt++)
#pragma unroll
                for (int r = 0; r < 4; r++) O[nt][r] *= alpha;
        }
        int c0 = l15 + cw;
        int c1 = l15 + 16 - cw;
#pragma unroll
        for (int r = 0; r < 4; r++) {
            float e0v = EXP2(lg0[r] - m_w);
            float e1v = EXP2(lg1[r] - m_w);
            l_i[r] += e0v + e1v;
#ifdef HAVE_PKBF16
            bfv2 pk2 = __builtin_amdgcn_cvt_pk_bf16_f32(e0v, e1v);
            PA[(rbase + r) * 40 + c0] = __builtin_bit_cast(u16, pk2[0]);
            PA[(rbase + r) * 40 + c1] = __builtin_bit_cast(u16, pk2[1]);
#else
            PA[(rbase + r) * 40 + c0] = f2bf(e0v);
            PA[(rbase + r) * 40 + c1] = f2bf(e1v);
#endif
        }

        // ---- O += P.V (swizzled A read; V from direct-global regs)
        {
            s16x8 ap = *(const s16x8*)&PA[pard];
            O[0] = __builtin_amdgcn_mfma_f32_16x16x32_bf16(ap, bv0, O[0], 0, 0, 0);
            O[1] = __builtin_amdgcn_mfma_f32_16x16x32_bf16(ap, bv1, O[1], 0, 0, 0);
            O[2] = __builtin_amdgcn_mfma_f32_16x16x32_bf16(ap, bv2, O[2], 0, 0, 0);
            O[3] = __builtin_amdgcn_mfma_f32_16x16x32_bf16(ap, bv3, O[3], 0, 0, 0);
        }
    }

    // epilogue: cross-lane l sum, write pre-split bf16 head
#pragma unroll
    for (int r = 0; r < 4; r++) {
        float l = l_i[r];
#pragma unroll
        for (int o = 1; o < 16; o <<= 1) l += __shfl_xor(l, o, 64);
        float inv = 1.0f / l;
        int grow = i0 + rbase + r;
        u16* dst = head16 + (size_t)(b * Sx + grow) * 2048 + h * 64 + l15;
#pragma unroll
        for (int nt = 0; nt < 4; nt++) {
            float f = O[nt][r] * inv;
            u16 hh = f2bf(f);
            dst[16 * nt]        = hh;
            dst[1024 + 16 * nt] = f2bf(f - bf2f(hh));
        }
    }
}

// ---------------------------------------------------------------- launcher
extern "C" void kernel_launch(void* const* d_in, const int* in_sizes, int n_in,
                              void* d_out, int out_size, void* d_ws, size_t ws_size,
                              hipStream_t stream) {
    const float* x    = (const float*)d_in[0];
    const float* ln_g = (const float*)d_in[1];
    const float* ln_b = (const float*)d_in[2];
    const float* Wq   = (const float*)d_in[3];
    const float* bq   = (const float*)d_in[4];
    const float* Wk   = (const float*)d_in[5];
    const float* bk   = (const float*)d_in[6];
    const float* Wv   = (const float*)d_in[7];
    const float* bv   = (const float*)d_in[8];
    const float* Wp   = (const float*)d_in[9];
    const float* Wo   = (const float*)d_in[10];
    const float* bo   = (const float*)d_in[11];
    const float* ub   = (const float*)d_in[12];
    const float* vbias= (const float*)d_in[13];

    float* out = (float*)d_out;
    u16* base  = (u16*)d_ws;

    const int MROWS = 2 * Sx;                          // 4096
    u16* xn16   = base;                                // [4096][2048] hi|lo
    u16* head16 = base + 8u  * 1024 * 1024;            // [4096][2048] hi|lo
    u16* pe16   = base + 16u * 1024 * 1024;            // [2048][2048] hi|lo
    u16* qb16   = base + 20u * 1024 * 1024;            // [4096][1024]
    u16* kb16   = base + 24u * 1024 * 1024;
    u16* vb16   = base + 28u * 1024 * 1024;
    u16* pp16   = base + 32u * 1024 * 1024;            // [2048][1024]
    u16* vT16   = base + 34u * 1024 * 1024;            // [2][16][64][64][32]
    u16* WT     = base + 38u * 1024 * 1024;            // 5 x [1024][2048]
    float* ukg  = (float*)(base + 48u * 1024 * 1024);
    float* vbg  = ukg + 2 * Hh * Sx;

    ln_kernel<<<MROWS, 256, 0, stream>>>(x, ln_g, ln_b, xn16);
    pe_kernel<<<Sx * 512 / 256, 256, 0, stream>>>(pe16);

    dim3 gw(32, 32, 5);
    wconv_kernel<<<gw, 256, 0, stream>>>(Wq, Wk, Wv, Wp, Wo, WT);

    dim3 g1(8, MROWS / 64);
    dim3 g2(8, Sx / 64);
    gemm_bf16x3<<<g1, 256, 0, stream>>>(xn16, WT + 0u * 1024 * 2048, bq, 1.0f,      nullptr, qb16, MROWS);
    gemm_bf16x3<<<g1, 256, 0, stream>>>(xn16, WT + 1u * 1024 * 2048, bk, ATT_SCALE, nullptr, kb16, MROWS);
    gemm_bf16x3<<<g1, 256, 0, stream>>>(xn16, WT + 2u * 1024 * 2048, bv, 1.0f,      nullptr, vb16, MROWS);
    gemm_bf16x3<<<g2, 256, 0, stream>>>(pe16, WT + 3u * 1024 * 2048, nullptr, ATT_SCALE, nullptr, pp16, Sx);

    dim3 gv(Sx / 32, Hh, 2);
    vtrans_kernel<<<gv, 256, 0, stream>>>(vb16, vT16);

    ukvb_kernel<<<(2 * Hh * Sx + Hh * Sx) / 256, 256, 0, stream>>>(kb16, pp16, ub, vbias, ukg, vbg);

    flash_kernel<<<2 * Hh * 32, 256, 0, stream>>>(qb16, kb16, vT16, pp16, ukg, vbg, head16);

    gemm_bf16x3<<<g1, 256, 0, stream>>>(head16, WT + 4u * 1024 * 2048, bo, 1.0f, out, nullptr, MROWS);
}

// Round 4
// 405.339 us; speedup vs baseline: 1.7039x; 1.1205x over previous
//
#include <hip/hip_runtime.h>
#include <hip/hip_bf16.h>
#include <math.h>

#define Dm   1024
#define Hh   16
#define Sx   2048

typedef short s16x8 __attribute__((ext_vector_type(8)));
typedef float f32x4 __attribute__((ext_vector_type(4)));
typedef unsigned short u16;
typedef u16 u16x4 __attribute__((ext_vector_type(4)));

#if defined(__has_builtin)
#  if __has_builtin(__builtin_amdgcn_cvt_pk_bf16_f32)
#    define HAVE_PKBF16 1
typedef __bf16 bfv2 __attribute__((ext_vector_type(2)));
#  endif
#  if __has_builtin(__builtin_amdgcn_exp2f)
#    define EXP2(x) __builtin_amdgcn_exp2f(x)
#  endif
#endif
#ifndef EXP2
#  define EXP2(x) exp2f(x)
#endif

// logit scale folded into k and p: dh^-0.5 * log2(e)
#define ATT_SCALE 0.1803368801111204f

__device__ __forceinline__ float wave_sum64(float v) {
#pragma unroll
    for (int o = 32; o > 0; o >>= 1) v += __shfl_xor(v, o, 64);
    return v;
}
__device__ __forceinline__ u16 f2bf(float x) {
    unsigned int u = __float_as_uint(x);
    unsigned int r = u + 0x7FFFu + ((u >> 16) & 1u);
    return (u16)(r >> 16);
}
__device__ __forceinline__ float bf2f(u16 h) {
    return __uint_as_float(((unsigned int)h) << 16);
}
__device__ __forceinline__ f32x4 mfma16(s16x8 a, s16x8 b, f32x4 c) {
    return __builtin_amdgcn_mfma_f32_16x16x32_bf16(a, b, c, 0, 0, 0);
}

// ---------------------------------------------------------------- LayerNorm -> pre-split bf16 hi|lo
__global__ __launch_bounds__(256) void ln_kernel(const float* __restrict__ x,
                                                 const float* __restrict__ g,
                                                 const float* __restrict__ b,
                                                 u16* __restrict__ out16) {
    int row = blockIdx.x;
    int tid = threadIdx.x;
    const float4* xr = (const float4*)(x + (size_t)row * Dm);
    float4 v = xr[tid];
    float s  = v.x + v.y + v.z + v.w;
    float ss = v.x * v.x + v.y * v.y + v.z * v.z + v.w * v.w;
    __shared__ float rbuf[8];
    s  = wave_sum64(s);
    ss = wave_sum64(ss);
    if ((tid & 63) == 0) { rbuf[tid >> 6] = s; rbuf[4 + (tid >> 6)] = ss; }
    __syncthreads();
    float mean = (rbuf[0] + rbuf[1] + rbuf[2] + rbuf[3]) * (1.0f / Dm);
    float msq  = (rbuf[4] + rbuf[5] + rbuf[6] + rbuf[7]) * (1.0f / Dm);
    float var  = msq - mean * mean;
    float rstd = 1.0f / sqrtf(var + 1e-5f);
    float4 gg = ((const float4*)g)[tid];
    float4 bb = ((const float4*)b)[tid];
    float o[4];
    o[0] = (v.x - mean) * rstd * gg.x + bb.x;
    o[1] = (v.y - mean) * rstd * gg.y + bb.y;
    o[2] = (v.z - mean) * rstd * gg.z + bb.z;
    o[3] = (v.w - mean) * rstd * gg.w + bb.w;
    u16x4 hi, lo;
#pragma unroll
    for (int i = 0; i < 4; i++) {
        u16 h = f2bf(o[i]);
        hi[i] = h;
        lo[i] = f2bf(o[i] - bf2f(h));
    }
    *(u16x4*)&out16[(size_t)row * 2048 + tid * 4]        = hi;
    *(u16x4*)&out16[(size_t)row * 2048 + 1024 + tid * 4] = lo;
}

// ---------------------------------------------------------------- sinusoidal PE -> pre-split bf16
__global__ __launch_bounds__(256) void pe_kernel(u16* __restrict__ pe16) {
    int idx = blockIdx.x * 256 + threadIdx.x;
    int r = idx >> 9;
    int t = idx & 511;
    double div = exp((double)(2 * t) * (-9.210340371976184 / 1024.0));
    double ang = (double)r * div;
    float sv = (float)sin(ang), cv = (float)cos(ang);
    u16 sh = f2bf(sv), chh = f2bf(cv);
    u16* row = pe16 + (size_t)r * 2048;
    row[2 * t]            = sh;
    row[2 * t + 1]        = chh;
    row[1024 + 2 * t]     = f2bf(sv - bf2f(sh));
    row[1024 + 2 * t + 1] = f2bf(cv - bf2f(chh));
}

// ---------------------------------------------------------------- weight transpose + bf16 hi/lo split
__global__ __launch_bounds__(256) void wconv_kernel(const float* __restrict__ W0,
                                                    const float* __restrict__ W1,
                                                    const float* __restrict__ W2,
                                                    const float* __restrict__ W3,
                                                    const float* __restrict__ W4,
                                                    u16* __restrict__ WT) {
    int wz = blockIdx.z;
    const float* W = (wz == 0) ? W0 : (wz == 1) ? W1 : (wz == 2) ? W2 : (wz == 3) ? W3 : W4;
    u16* T = WT + (size_t)wz * 1024 * 2048;
    __shared__ float tile[32][33];
    int n0 = blockIdx.x * 32, k0 = blockIdx.y * 32;
    int tx = threadIdx.x & 31, ty = threadIdx.x >> 5;
#pragma unroll
    for (int r = 0; r < 32; r += 8)
        tile[ty + r][tx] = W[(size_t)(k0 + ty + r) * 1024 + n0 + tx];
    __syncthreads();
#pragma unroll
    for (int r = 0; r < 32; r += 8) {
        int n = ty + r;
        float x = tile[tx][n];
        u16 h = f2bf(x);
        float rem = x - bf2f(h);
        T[(size_t)(n0 + n) * 2048 + k0 + tx]        = h;
        T[(size_t)(n0 + n) * 2048 + 1024 + k0 + tx] = f2bf(rem);
    }
}

// ---------------------------------------------------------------- 128x128 bf16x3 MFMA GEMM
// mode 0: fused Q/K/V/P projections, 1D grid 896 = 768 QKV tiles (24x32) + 128 pe tiles (8x16).
//         widx 0..3 selects weight slot, bias, scale; outputs at Cb + widx*4M (contiguous ws).
// mode 1: head GEMM, 2D grid (8,32), weight slot 4, float output C.
// 2x2 waves, 4x4 16x16x32 fragments/wave (48 MFMA per wave per K-step of 32), reg-staged
// single-buffer 2-barrier loop -- same addressing/accumulation order as the proven 64x128
// kernel, so outputs are bit-identical.
__global__ __launch_bounds__(256, 3) void gemm128(const u16* __restrict__ A,
                                                  const u16* __restrict__ A2,
                                                  const u16* __restrict__ WT,
                                                  const float* __restrict__ b0,
                                                  const float* __restrict__ b1,
                                                  const float* __restrict__ b2,
                                                  u16* __restrict__ Cb,
                                                  float* __restrict__ C,
                                                  int mode) {
    __shared__ __align__(16) u16 Ah[128 * 72];
    __shared__ __align__(16) u16 Bh[128 * 72];
    int tid = threadIdx.x;
    int gx, gy, widx;
    const u16* Asrc = A;
    if (mode == 0) {
        int bid = blockIdx.x;
        if (bid < 768) { gx = bid % 24; gy = bid / 24; widx = gx >> 3; gx &= 7; }
        else           { int r2 = bid - 768; gx = r2 & 7; gy = r2 >> 3; widx = 3; Asrc = A2; }
    } else {
        gx = blockIdx.x; gy = blockIdx.y; widx = 4;
    }
    int bn = gx * 128, bm = gy * 128;
    const u16* Wb = WT + (size_t)widx * (1024 * 2048);
    const float* bias = (widx == 0) ? b0 : (widx == 1) ? b1 : (widx == 2) ? b2
                      : (widx == 4) ? b0 : nullptr;
    float csc = (widx == 1 || widx == 3) ? ATT_SCALE : 1.0f;

    int w = tid >> 6, ln = tid & 63, g = ln >> 4, l15 = ln & 15;
    int wm = (w & 1) * 64, wn = (w >> 1) * 64;

    // staging map: thread covers rows (tid>>3)+{0,32,64,96}, chunk c8 = tid&7 (half|quarter)
    int srow = tid >> 3, c8 = tid & 7;
    int half = c8 >> 2, cIn = c8 & 3;
    const u16* Agp = Asrc + (size_t)(bm + srow) * 2048 + half * 1024 + cIn * 8;
    const u16* Bgp = Wb   + (size_t)(bn + srow) * 2048 + half * 1024 + cIn * 8;
    u16* Aw = &Ah[srow * 72 + half * 32 + cIn * 8];
    u16* Bw = &Bh[srow * 72 + half * 32 + cIn * 8];

    f32x4 acc[4][4] = {};

    s16x8 pa0 = *(const s16x8*)(Agp);
    s16x8 pa1 = *(const s16x8*)(Agp + 65536);
    s16x8 pa2 = *(const s16x8*)(Agp + 131072);
    s16x8 pa3 = *(const s16x8*)(Agp + 196608);
    s16x8 pb0 = *(const s16x8*)(Bgp);
    s16x8 pb1 = *(const s16x8*)(Bgp + 65536);
    s16x8 pb2 = *(const s16x8*)(Bgp + 131072);
    s16x8 pb3 = *(const s16x8*)(Bgp + 196608);

    for (int k0 = 0; k0 < 1024; k0 += 32) {
        __syncthreads();                         // B0: prev-tile fragment reads done
        *(s16x8*)(Aw)           = pa0;
        *(s16x8*)(Aw + 32 * 72) = pa1;
        *(s16x8*)(Aw + 64 * 72) = pa2;
        *(s16x8*)(Aw + 96 * 72) = pa3;
        *(s16x8*)(Bw)           = pb0;
        *(s16x8*)(Bw + 32 * 72) = pb1;
        *(s16x8*)(Bw + 64 * 72) = pb2;
        *(s16x8*)(Bw + 96 * 72) = pb3;
        int kn = k0 + 32;                        // overrun at kn=1024 stays in workspace
        pa0 = *(const s16x8*)(Agp + kn);
        pa1 = *(const s16x8*)(Agp + 65536 + kn);
        pa2 = *(const s16x8*)(Agp + 131072 + kn);
        pa3 = *(const s16x8*)(Agp + 196608 + kn);
        pb0 = *(const s16x8*)(Bgp + kn);
        pb1 = *(const s16x8*)(Bgp + 65536 + kn);
        pb2 = *(const s16x8*)(Bgp + 131072 + kn);
        pb3 = *(const s16x8*)(Bgp + 196608 + kn);
        __syncthreads();                         // B1: LDS tile ready

        s16x8 bhf[4], blf[4];
#pragma unroll
        for (int nt = 0; nt < 4; nt++) {
            int br = (wn + nt * 16 + l15) * 72;
            bhf[nt] = *(const s16x8*)&Bh[br + g * 8];
            blf[nt] = *(const s16x8*)&Bh[br + 32 + g * 8];
        }
#pragma unroll
        for (int mt = 0; mt < 4; mt++) {
            int ar = (wm + mt * 16 + l15) * 72;
            s16x8 ah = *(const s16x8*)&Ah[ar + g * 8];
            s16x8 al = *(const s16x8*)&Ah[ar + 32 + g * 8];
#pragma unroll
            for (int nt = 0; nt < 4; nt++) {
                acc[mt][nt] = mfma16(ah, bhf[nt], acc[mt][nt]);
                acc[mt][nt] = mfma16(al, bhf[nt], acc[mt][nt]);
                acc[mt][nt] = mfma16(ah, blf[nt], acc[mt][nt]);
            }
        }
    }

    float bv4[4];
#pragma unroll
    for (int nt = 0; nt < 4; nt++)
        bv4[nt] = bias ? bias[bn + wn + nt * 16 + l15] : 0.0f;
    if (mode == 0) {
        u16* Co = Cb + (size_t)widx * (4096 * 1024);
#pragma unroll
        for (int mt = 0; mt < 4; mt++)
#pragma unroll
            for (int r = 0; r < 4; r++) {
                int row = bm + wm + mt * 16 + g * 4 + r;
                u16* cp = Co + (size_t)row * 1024 + bn + wn + l15;
#pragma unroll
                for (int nt = 0; nt < 4; nt++)
                    cp[16 * nt] = f2bf((acc[mt][nt][r] + bv4[nt]) * csc);
            }
    } else {
#pragma unroll
        for (int mt = 0; mt < 4; mt++)
#pragma unroll
            for (int r = 0; r < 4; r++) {
                int row = bm + wm + mt * 16 + g * 4 + r;
                float* cp = C + (size_t)row * 1024 + bn + wn + l15;
#pragma unroll
                for (int nt = 0; nt < 4; nt++)
                    cp[16 * nt] = acc[mt][nt][r] + bv4[nt];
            }
    }
}

// ---------------------------------------------------------------- V transpose to tiled [b][h][jt][d][32]
__global__ __launch_bounds__(256) void vtrans_kernel(const u16* __restrict__ v,
                                                     u16* __restrict__ vT) {
    __shared__ u16 L[32 * 72];
    int jt = blockIdx.x, h = blockIdx.y, b = blockIdx.z;
    int tid = threadIdx.x;
    int row = tid >> 3, cc = tid & 7;
    const u16* src = v + ((size_t)(b * Sx + jt * 32 + row)) * Dm + h * 64 + cc * 8;
    *(s16x8*)&L[row * 72 + cc * 8] = *(const s16x8*)src;
    __syncthreads();
    int d = tid >> 2, jq = tid & 3;
    s16x8 o;
#pragma unroll
    for (int jj = 0; jj < 8; jj++) o[jj] = (short)L[(jq * 8 + jj) * 72 + d];
    u16* dst = vT + (((size_t)(b * 16 + h) * 64 + jt)) * 2048 + d * 32 + jq * 8;
    *(s16x8*)dst = o;
}

// ---------------------------------------------------------------- precompute u.k_j and vb.p_r (bf16 in; k/p pre-scaled)
__global__ __launch_bounds__(256) void ukvb_kernel(const u16* __restrict__ k,
                                                   const u16* __restrict__ pp,
                                                   const float* __restrict__ u,
                                                   const float* __restrict__ vb,
                                                   float* __restrict__ ukg,
                                                   float* __restrict__ vbg) {
    int jid = blockIdx.x * 256 + threadIdx.x;
    const u16* src; const float* vec; float* dst; int idx;
    if (jid < 2 * Hh * Sx) {
        int j = jid & 2047, h = (jid >> 11) & 15, b = jid >> 15;
        src = k + ((size_t)(b * Sx + j)) * Dm + h * 64;
        vec = u + h * 64; dst = ukg; idx = jid;
    } else {
        int j2 = jid - 2 * Hh * Sx;
        int r = j2 & 2047, h = j2 >> 11;
        src = pp + (size_t)r * Dm + h * 64;
        vec = vb + h * 64; dst = vbg; idx = j2;
    }
    float s = 0.0f;
#pragma unroll
    for (int c = 0; c < 8; c++) {
        s16x8 kk = *(const s16x8*)(src + c * 8);
#pragma unroll
        for (int i = 0; i < 8; i++) s += bf2f((u16)kk[i]) * vec[c * 8 + i];
    }
    dst[idx] = s;
}

// ---------------------------------------------------------------- MFMA helpers for flash
__device__ __forceinline__ void wfill2(s16x8 a0, s16x8 a1, const u16* PW,
                                       int g, int l15, f32x4& d0, f32x4& d1) {
    f32x4 z = {0.f, 0.f, 0.f, 0.f};
    s16x8 b00 = *(const s16x8*)&PW[l15 * 72 + g * 8];
    s16x8 b01 = *(const s16x8*)&PW[l15 * 72 + 32 + g * 8];
    s16x8 b10 = *(const s16x8*)&PW[(16 + l15) * 72 + g * 8];
    s16x8 b11 = *(const s16x8*)&PW[(16 + l15) * 72 + 32 + g * 8];
    d0 = __builtin_amdgcn_mfma_f32_16x16x32_bf16(a0, b00, z, 0, 0, 0);
    d0 = __builtin_amdgcn_mfma_f32_16x16x32_bf16(a1, b01, d0, 0, 0, 0);
    d1 = __builtin_amdgcn_mfma_f32_16x16x32_bf16(a0, b10, z, 0, 0, 0);
    d1 = __builtin_amdgcn_mfma_f32_16x16x32_bf16(a1, b11, d1, 0, 0, 0);
}

// fill window chunk: skewed circular slots, physical = (logical_vr + row) % 96, stride 98
__device__ __forceinline__ void window_fill(s16x8 aq0, s16x8 aq1, s16x8 ab0, s16x8 ab1,
                                            const u16* PW, float* Ws,
                                            const float* __restrict__ vbb,
                                            int vstart, int sb, int rbase, int g, int l15) {
    f32x4 e0, e1;
    if (vstart + 31 <= Sx) {
        wfill2(aq0, aq1, PW, g, l15, e0, e1);
    } else if (vstart > Sx) {
        wfill2(ab0, ab1, PW, g, l15, e0, e1);
    } else {
        f32x4 d0, d1, f0, f1;
        wfill2(aq0, aq1, PW, g, l15, d0, d1);
        wfill2(ab0, ab1, PW, g, l15, f0, f1);
        int v0 = vstart + l15, v1 = vstart + 16 + l15;
#pragma unroll
        for (int r = 0; r < 4; r++) {
            e0[r] = (v0 > Sx) ? f0[r] : d0[r];
            e1[r] = (v1 > Sx) ? f1[r] : d1[r];
        }
    }
    int v0 = vstart + l15, v1 = vstart + 16 + l15;
    int pc0 = v0 < Sx ? v0 : v0 - Sx - 1;
    int pc1 = v1 < Sx ? v1 : v1 - Sx - 1;
    float vb0 = (v0 == Sx) ? 0.0f : vbb[pc0];
    float vb1 = (v1 == Sx) ? 0.0f : vbb[pc1];
    int bs = sb + rbase;
#pragma unroll
    for (int r = 0; r < 4; r++) {
        int b2 = bs + r; if (b2 >= 96) b2 -= 96;
        int sl0 = b2 + l15; if (sl0 >= 96) sl0 -= 96;
        int sl1 = sl0 + 16; if (sl1 >= 96) sl1 -= 96;
        Ws[(rbase + r) * 98 + sl0] = (v0 == Sx) ? 0.0f : e0[r] + vb0;
        Ws[(rbase + r) * 98 + sl1] = (v1 == Sx) ? 0.0f : e1[r] + vb1;
    }
}

// ---------------------------------------------------------------- flash attention (round-3, frozen)
__global__ __launch_bounds__(256, 4) void flash_kernel(const u16* __restrict__ q,
                                                       const u16* __restrict__ k,
                                                       const u16* __restrict__ vt,
                                                       const u16* __restrict__ pp,
                                                       const float* __restrict__ ukg,
                                                       const float* __restrict__ vbg,
                                                       u16* __restrict__ head16) {
    __shared__ __align__(16) unsigned char smem[39424];
    float* Ws = (float*)smem;                    // 64*98*4 = 25088 (live whole kernel)
    u16*   Qs = (u16*)smem;                      // 65*72*2 = 9360  (prologue only, aliased)
    u16*   Kt = (u16*)(smem + 25088);            // 32*72*2 = 4608
    u16*   PW = (u16*)(smem + 29696);            // 32*72*2 = 4608
    u16*   PA = (u16*)(smem + 34304);            // 64*40*2 = 5120

    int tid = threadIdx.x, blk = blockIdx.x;
    int grp = (blk & 7) + 8 * (blk >> 8);        // 0..31 = b*16 + h
    int it  = (blk >> 3) & 31;
    int h = grp & 15, b = grp >> 4;
    int i0 = it * 64;
    int a0 = 1984 - i0;

    const u16* qb  = q  + ((size_t)b * Sx) * Dm + h * 64;
    const u16* kb  = k  + ((size_t)b * Sx) * Dm + h * 64;
    const u16* vtb = vt + ((size_t)(b * 16 + h) * 64) * 2048;
    const u16* ppb = pp + h * 64;
    const float* ukb = ukg + (size_t)(b * Hh + h) * Sx;
    const float* vbb = vbg + (size_t)h * Sx;

    int w = tid >> 6, ln = tid & 63, g = ln >> 4, l15 = ln & 15;
    int rv = tid >> 3, ch = tid & 7;
    int rbase = 16 * w + 4 * g;

    for (int c = tid; c < 65 * 8; c += 256) {
        int row = c >> 3, cc = c & 7;
        int i = i0 + row;
        s16x8 tv = {0, 0, 0, 0, 0, 0, 0, 0};
        if (i < Sx) tv = *(const s16x8*)(qb + (size_t)i * Dm + cc * 8);
        *(s16x8*)&Qs[row * 72 + cc * 8] = tv;
    }
    __syncthreads();

    s16x8 aq0 = *(const s16x8*)&Qs[(16 * w + l15) * 72 + g * 8];
    s16x8 aq1 = *(const s16x8*)&Qs[(16 * w + l15) * 72 + 32 + g * 8];
    s16x8 ab0 = *(const s16x8*)&Qs[(16 * w + 1 + l15) * 72 + g * 8];
    s16x8 ab1 = *(const s16x8*)&Qs[(16 * w + 1 + l15) * 72 + 32 + g * 8];
    __syncthreads();     // all waves done reading Qs before any Ws write (aliased)

    for (int f = 0; f < 3; f++) {
        int vrb = f * 32;
        if (f) __syncthreads();
        {
            int vv = a0 + vrb + rv;
            s16x8 tv = {0, 0, 0, 0, 0, 0, 0, 0};
            if (vv != Sx) {
                int pc = vv < Sx ? vv : vv - Sx - 1;
                tv = *(const s16x8*)(ppb + (size_t)pc * Dm + ch * 8);
            }
            *(s16x8*)&PW[rv * 72 + ch * 8] = tv;
        }
        __syncthreads();
        window_fill(aq0, aq1, ab0, ab1, PW, Ws, vbb, a0 + vrb, vrb, rbase, g, l15);
    }

    f32x4 O[4] = {{0.f,0.f,0.f,0.f},{0.f,0.f,0.f,0.f},{0.f,0.f,0.f,0.f},{0.f,0.f,0.f,0.f}};
    float m_w = -1e30f;
    float l_i[4] = {0.f, 0.f, 0.f, 0.f};
    int wro[4];
#pragma unroll
    for (int r = 0; r < 4; r++) wro[r] = (rbase + r) * 98;
    int sb = 0;
    int jm = 63;
    int cw = (g >= 2) ? 16 : 0;
    int crd = (l15 >> 3) << 4;
    int pard = (16 * w + l15) * 40 + ((g * 8 + crd) & 31);

    const u16* pK = kb + (size_t)rv * Dm + ch * 8;
    const u16* pV = vtb + l15 * 32 + g * 8;
    s16x8 rK = *(const s16x8*)pK;
    s16x8 rPW = {0, 0, 0, 0, 0, 0, 0, 0};

    for (int t = 0; t < 64; t++) {
        int j0 = t * 32;
        __syncthreads();   // B0
        *(s16x8*)&Kt[rv * 72 + ch * 8] = rK;
        if (t >= 1) *(s16x8*)&PW[rv * 72 + ch * 8] = rPW;

        s16x8 bv0 = *(const s16x8*)(pV);
        s16x8 bv1 = *(const s16x8*)(pV + 512);
        s16x8 bv2 = *(const s16x8*)(pV + 1024);
        s16x8 bv3 = *(const s16x8*)(pV + 1536);
        pV += 2048;

        pK += 32 * Dm;
        rK = *(const s16x8*)pK;
        {
            int vv = a0 + (t + 3) * 32 + rv;
            s16x8 z8 = {0, 0, 0, 0, 0, 0, 0, 0};
            if (vv != Sx) {
                int pc = vv < Sx ? vv : vv - Sx - 1;
                if (pc > Sx - 1) pc = Sx - 1;
                z8 = *(const s16x8*)(ppb + (size_t)pc * Dm + ch * 8);
            }
            rPW = z8;
        }
        float uk0 = ukb[j0 + l15];
        float uk1 = ukb[j0 + 16 + l15];
        __syncthreads();   // B1

        f32x4 s0, s1;
        {
            f32x4 z = {0.f, 0.f, 0.f, 0.f};
            s16x8 bk00 = *(const s16x8*)&Kt[l15 * 72 + g * 8];
            s16x8 bk01 = *(const s16x8*)&Kt[l15 * 72 + 32 + g * 8];
            s16x8 bk10 = *(const s16x8*)&Kt[(16 + l15) * 72 + g * 8];
            s16x8 bk11 = *(const s16x8*)&Kt[(16 + l15) * 72 + 32 + g * 8];
            s0 = __builtin_amdgcn_mfma_f32_16x16x32_bf16(aq0, bk00, z, 0, 0, 0);
            s0 = __builtin_amdgcn_mfma_f32_16x16x32_bf16(aq1, bk01, s0, 0, 0, 0);
            s1 = __builtin_amdgcn_mfma_f32_16x16x32_bf16(aq0, bk10, z, 0, 0, 0);
            s1 = __builtin_amdgcn_mfma_f32_16x16x32_bf16(aq1, bk11, s1, 0, 0, 0);
        }

        if (t >= 1) {
            window_fill(aq0, aq1, ab0, ab1, PW, Ws, vbb, a0 + j0 + 64, sb, rbase, g, l15);
            sb += 32; if (sb >= 96) sb -= 96;
        }

        int si0 = jm + l15; if (si0 >= 96) si0 -= 96;
        int si1 = si0 + 16; if (si1 >= 96) si1 -= 96;
        jm += 32; if (jm >= 96) jm -= 96;
        float lg0[4], lg1[4];
#pragma unroll
        for (int r = 0; r < 4; r++) {
            lg0[r] = s0[r] + uk0 + Ws[wro[r] + si0];
            lg1[r] = s1[r] + uk1 + Ws[wro[r] + si1];
        }
        float pmax = fmaxf(fmaxf(fmaxf(lg0[0], lg1[0]), fmaxf(lg0[1], lg1[1])),
                           fmaxf(fmaxf(lg0[2], lg1[2]), fmaxf(lg0[3], lg1[3])));
        if (__any(pmax > m_w + 8.0f)) {
            float mx = pmax;
#pragma unroll
            for (int o = 1; o < 64; o <<= 1) mx = fmaxf(mx, __shfl_xor(mx, o, 64));
            float alpha = EXP2(m_w - mx);
            m_w = mx;
            l_i[0] *= alpha; l_i[1] *= alpha; l_i[2] *= alpha; l_i[3] *= alpha;
#pragma unroll
            for (int nt = 0; nt < 4; nt++)
#pragma unroll
                for (int r = 0; r < 4; r++) O[nt][r] *= alpha;
        }
        int c0 = l15 + cw;
        int c1 = l15 + 16 - cw;
#pragma unroll
        for (int r = 0; r < 4; r++) {
            float e0v = EXP2(lg0[r] - m_w);
            float e1v = EXP2(lg1[r] - m_w);
            l_i[r] += e0v + e1v;
#ifdef HAVE_PKBF16
            bfv2 pk2 = __builtin_amdgcn_cvt_pk_bf16_f32(e0v, e1v);
            PA[(rbase + r) * 40 + c0] = __builtin_bit_cast(u16, pk2[0]);
            PA[(rbase + r) * 40 + c1] = __builtin_bit_cast(u16, pk2[1]);
#else
            PA[(rbase + r) * 40 + c0] = f2bf(e0v);
            PA[(rbase + r) * 40 + c1] = f2bf(e1v);
#endif
        }

        {
            s16x8 ap = *(const s16x8*)&PA[pard];
            O[0] = __builtin_amdgcn_mfma_f32_16x16x32_bf16(ap, bv0, O[0], 0, 0, 0);
            O[1] = __builtin_amdgcn_mfma_f32_16x16x32_bf16(ap, bv1, O[1], 0, 0, 0);
            O[2] = __builtin_amdgcn_mfma_f32_16x16x32_bf16(ap, bv2, O[2], 0, 0, 0);
            O[3] = __builtin_amdgcn_mfma_f32_16x16x32_bf16(ap, bv3, O[3], 0, 0, 0);
        }
    }

#pragma unroll
    for (int r = 0; r < 4; r++) {
        float l = l_i[r];
#pragma unroll
        for (int o = 1; o < 16; o <<= 1) l += __shfl_xor(l, o, 64);
        float inv = 1.0f / l;
        int grow = i0 + rbase + r;
        u16* dst = head16 + (size_t)(b * Sx + grow) * 2048 + h * 64 + l15;
#pragma unroll
        for (int nt = 0; nt < 4; nt++) {
            float f = O[nt][r] * inv;
            u16 hh = f2bf(f);
            dst[16 * nt]        = hh;
            dst[1024 + 16 * nt] = f2bf(f - bf2f(hh));
        }
    }
}

// ---------------------------------------------------------------- launcher
extern "C" void kernel_launch(void* const* d_in, const int* in_sizes, int n_in,
                              void* d_out, int out_size, void* d_ws, size_t ws_size,
                              hipStream_t stream) {
    const float* x    = (const float*)d_in[0];
    const float* ln_g = (const float*)d_in[1];
    const float* ln_b = (const float*)d_in[2];
    const float* Wq   = (const float*)d_in[3];
    const float* bq   = (const float*)d_in[4];
    const float* Wk   = (const float*)d_in[5];
    const float* bk   = (const float*)d_in[6];
    const float* Wv   = (const float*)d_in[7];
    const float* bv   = (const float*)d_in[8];
    const float* Wp   = (const float*)d_in[9];
    const float* Wo   = (const float*)d_in[10];
    const float* bo   = (const float*)d_in[11];
    const float* ub   = (const float*)d_in[12];
    const float* vbias= (const float*)d_in[13];

    float* out = (float*)d_out;
    u16* base  = (u16*)d_ws;

    const int MROWS = 2 * Sx;                          // 4096
    u16* xn16   = base;                                // [4096][2048] hi|lo
    u16* head16 = base + 8u  * 1024 * 1024;            // [4096][2048] hi|lo
    u16* pe16   = base + 16u * 1024 * 1024;            // [2048][2048] hi|lo
    u16* qb16   = base + 20u * 1024 * 1024;            // [4096][1024]; k/v/p at +4M strides
    u16* kb16   = base + 24u * 1024 * 1024;
    u16* vb16   = base + 28u * 1024 * 1024;
    u16* pp16   = base + 32u * 1024 * 1024;            // [2048][1024]
    u16* vT16   = base + 34u * 1024 * 1024;            // [2][16][64][64][32]
    u16* WT     = base + 38u * 1024 * 1024;            // 5 x [1024][2048]
    float* ukg  = (float*)(base + 48u * 1024 * 1024);
    float* vbg  = ukg + 2 * Hh * Sx;

    ln_kernel<<<MROWS, 256, 0, stream>>>(x, ln_g, ln_b, xn16);
    pe_kernel<<<Sx * 512 / 256, 256, 0, stream>>>(pe16);

    dim3 gw(32, 32, 5);
    wconv_kernel<<<gw, 256, 0, stream>>>(Wq, Wk, Wv, Wp, Wo, WT);

    // fused Q/K/V/P projections: 768 QKV tiles + 128 pe tiles
    gemm128<<<896, 256, 0, stream>>>(xn16, pe16, WT, bq, bk, bv, qb16, nullptr, 0);

    dim3 gv(Sx / 32, Hh, 2);
    vtrans_kernel<<<gv, 256, 0, stream>>>(vb16, vT16);

    ukvb_kernel<<<(2 * Hh * Sx + Hh * Sx) / 256, 256, 0, stream>>>(kb16, pp16, ub, vbias, ukg, vbg);

    flash_kernel<<<2 * Hh * 32, 256, 0, stream>>>(qb16, kb16, vT16, pp16, ukg, vbg, head16);

    gemm128<<<dim3(8, 32), 256, 0, stream>>>(head16, nullptr, WT, bo, nullptr, nullptr, nullptr, out, 1);
}

// Round 5
// 387.043 us; speedup vs baseline: 1.7845x; 1.0473x over previous
//
#include <hip/hip_runtime.h>
#include <hip/hip_bf16.h>
#include <math.h>

#define Dm   1024
#define Hh   16
#define Sx   2048

typedef short s16x8 __attribute__((ext_vector_type(8)));
typedef float f32x4 __attribute__((ext_vector_type(4)));
typedef unsigned short u16;
typedef u16 u16x4 __attribute__((ext_vector_type(4)));

#if defined(__has_builtin)
#  if __has_builtin(__builtin_amdgcn_cvt_pk_bf16_f32)
#    define HAVE_PKBF16 1
typedef __bf16 bfv2 __attribute__((ext_vector_type(2)));
#  endif
#  if __has_builtin(__builtin_amdgcn_exp2f)
#    define EXP2(x) __builtin_amdgcn_exp2f(x)
#  endif
#endif
#ifndef EXP2
#  define EXP2(x) exp2f(x)
#endif

// logit scale folded into k and p: dh^-0.5 * log2(e)
#define ATT_SCALE 0.1803368801111204f

__device__ __forceinline__ float wave_sum64(float v) {
#pragma unroll
    for (int o = 32; o > 0; o >>= 1) v += __shfl_xor(v, o, 64);
    return v;
}
__device__ __forceinline__ u16 f2bf(float x) {
    unsigned int u = __float_as_uint(x);
    unsigned int r = u + 0x7FFFu + ((u >> 16) & 1u);
    return (u16)(r >> 16);
}
__device__ __forceinline__ float bf2f(u16 h) {
    return __uint_as_float(((unsigned int)h) << 16);
}
__device__ __forceinline__ f32x4 mfma16(s16x8 a, s16x8 b, f32x4 c) {
    return __builtin_amdgcn_mfma_f32_16x16x32_bf16(a, b, c, 0, 0, 0);
}
// direct global->LDS DMA, 16B/lane; LDS dest = wave-uniform base + lane*16
__device__ __forceinline__ void gl16(const u16* gp, u16* lp) {
    __builtin_amdgcn_global_load_lds(
        (__attribute__((address_space(1))) void*)(gp),
        (__attribute__((address_space(3))) void*)(lp), 16, 0, 0);
}

// ---------------------------------------------------------------- LayerNorm -> pre-split bf16 hi|lo
__global__ __launch_bounds__(256) void ln_kernel(const float* __restrict__ x,
                                                 const float* __restrict__ g,
                                                 const float* __restrict__ b,
                                                 u16* __restrict__ out16) {
    int row = blockIdx.x;
    int tid = threadIdx.x;
    const float4* xr = (const float4*)(x + (size_t)row * Dm);
    float4 v = xr[tid];
    float s  = v.x + v.y + v.z + v.w;
    float ss = v.x * v.x + v.y * v.y + v.z * v.z + v.w * v.w;
    __shared__ float rbuf[8];
    s  = wave_sum64(s);
    ss = wave_sum64(ss);
    if ((tid & 63) == 0) { rbuf[tid >> 6] = s; rbuf[4 + (tid >> 6)] = ss; }
    __syncthreads();
    float mean = (rbuf[0] + rbuf[1] + rbuf[2] + rbuf[3]) * (1.0f / Dm);
    float msq  = (rbuf[4] + rbuf[5] + rbuf[6] + rbuf[7]) * (1.0f / Dm);
    float var  = msq - mean * mean;
    float rstd = 1.0f / sqrtf(var + 1e-5f);
    float4 gg = ((const float4*)g)[tid];
    float4 bb = ((const float4*)b)[tid];
    float o[4];
    o[0] = (v.x - mean) * rstd * gg.x + bb.x;
    o[1] = (v.y - mean) * rstd * gg.y + bb.y;
    o[2] = (v.z - mean) * rstd * gg.z + bb.z;
    o[3] = (v.w - mean) * rstd * gg.w + bb.w;
    u16x4 hi, lo;
#pragma unroll
    for (int i = 0; i < 4; i++) {
        u16 h = f2bf(o[i]);
        hi[i] = h;
        lo[i] = f2bf(o[i] - bf2f(h));
    }
    *(u16x4*)&out16[(size_t)row * 2048 + tid * 4]        = hi;
    *(u16x4*)&out16[(size_t)row * 2048 + 1024 + tid * 4] = lo;
}

// ---------------------------------------------------------------- sinusoidal PE -> pre-split bf16
__global__ __launch_bounds__(256) void pe_kernel(u16* __restrict__ pe16) {
    int idx = blockIdx.x * 256 + threadIdx.x;
    int r = idx >> 9;
    int t = idx & 511;
    double div = exp((double)(2 * t) * (-9.210340371976184 / 1024.0));
    double ang = (double)r * div;
    float sv = (float)sin(ang), cv = (float)cos(ang);
    u16 sh = f2bf(sv), chh = f2bf(cv);
    u16* row = pe16 + (size_t)r * 2048;
    row[2 * t]            = sh;
    row[2 * t + 1]        = chh;
    row[1024 + 2 * t]     = f2bf(sv - bf2f(sh));
    row[1024 + 2 * t + 1] = f2bf(cv - bf2f(chh));
}

// ---------------------------------------------------------------- weight transpose + bf16 hi/lo split
__global__ __launch_bounds__(256) void wconv_kernel(const float* __restrict__ W0,
                                                    const float* __restrict__ W1,
                                                    const float* __restrict__ W2,
                                                    const float* __restrict__ W3,
                                                    const float* __restrict__ W4,
                                                    u16* __restrict__ WT) {
    int wz = blockIdx.z;
    const float* W = (wz == 0) ? W0 : (wz == 1) ? W1 : (wz == 2) ? W2 : (wz == 3) ? W3 : W4;
    u16* T = WT + (size_t)wz * 1024 * 2048;
    __shared__ float tile[32][33];
    int n0 = blockIdx.x * 32, k0 = blockIdx.y * 32;
    int tx = threadIdx.x & 31, ty = threadIdx.x >> 5;
#pragma unroll
    for (int r = 0; r < 32; r += 8)
        tile[ty + r][tx] = W[(size_t)(k0 + ty + r) * 1024 + n0 + tx];
    __syncthreads();
#pragma unroll
    for (int r = 0; r < 32; r += 8) {
        int n = ty + r;
        float x = tile[tx][n];
        u16 h = f2bf(x);
        float rem = x - bf2f(h);
        T[(size_t)(n0 + n) * 2048 + k0 + tx]        = h;
        T[(size_t)(n0 + n) * 2048 + 1024 + k0 + tx] = f2bf(rem);
    }
}

// ---------------------------------------------------------------- bf16x3 MFMA GEMM, global_load_lds staging
// BMT x 128 tile. Staging: direct global->LDS DMA (16B/lane), linear LDS [row][64 u16]
// with both-sides XOR swizzle: LDS chunk ch of row r holds global chunk ch^(r&7)
// (pre-swizzled per-lane SOURCE address; ds_read XORs the chunk index). Swizzle keys are
// loop-invariant. MFMA order identical to round-4 kernel -> bit-identical outputs.
// mode 0 (BMT=128): fused Q/K/V/P projections, grid 896 (768 QKV + 128 pe tiles).
// mode 1 (BMT=64):  head GEMM, grid (8,64) = 512 blocks -> 2 blocks/CU.
template<int BMT>
__global__ __launch_bounds__(256, 4) void gemm128k(const u16* __restrict__ A,
                                                   const u16* __restrict__ A2,
                                                   const u16* __restrict__ WT,
                                                   const float* __restrict__ b0,
                                                   const float* __restrict__ b1,
                                                   const float* __restrict__ b2,
                                                   u16* __restrict__ Cb,
                                                   float* __restrict__ C,
                                                   int mode) {
    constexpr int MT  = BMT / 32;     // fragment rows per wave
    constexpr int AC  = BMT / 32;     // A staging gloads per wave
    constexpr int RPW = BMT / 4;      // A rows staged per wave
    __shared__ __align__(16) u16 AhL[BMT * 64];
    __shared__ __align__(16) u16 BhL[128 * 64];
    int tid = threadIdx.x;
    int gx, gy, widx;
    const u16* Asrc = A;
    if (mode == 0) {
        int bid = blockIdx.x;
        if (bid < 768) { gx = bid % 24; gy = bid / 24; widx = gx >> 3; gx &= 7; }
        else           { int r2 = bid - 768; gx = r2 & 7; gy = r2 >> 3; widx = 3; Asrc = A2; }
    } else {
        gx = blockIdx.x; gy = blockIdx.y; widx = 4;
    }
    int bn = gx * 128, bm = gy * BMT;
    const u16* Wb = WT + (size_t)widx * (1024 * 2048);
    const float* bias = (widx == 0) ? b0 : (widx == 1) ? b1 : (widx == 2) ? b2
                      : (widx == 4) ? b0 : nullptr;
    float csc = (widx == 1 || widx == 3) ? ATT_SCALE : 1.0f;

    int w = tid >> 6, ln = tid & 63, g = ln >> 4, l15 = ln & 15;
    int wm = (w & 1) * (BMT / 2), wn = (w >> 1) * 64;

    // staging source map: lane l covers (row = base + (l>>3), LDS chunk = l&7);
    // global chunk = (l&7) ^ (l>>3)  [since row&7 == l>>3]
    int key = ln >> 3;
    int cg  = (ln & 7) ^ key;
    int gcol = (cg < 4) ? cg * 8 : 1024 + (cg - 4) * 8;   // u16 offset within row, +k0 later
    const u16* gA = Asrc + (size_t)(bm + w * RPW + key) * 2048 + gcol;
    const u16* gB = Wb   + (size_t)(bn + w * 32  + key) * 2048 + gcol;
    u16* lA = &AhL[(w * RPW) * 64];                       // wave-uniform LDS bases
    u16* lB = &BhL[(w * 32) * 64];

    // fragment read chunk swizzle (loop-invariant): row&7 == l15&7
    int keyr = l15 & 7;
    int chH = (g ^ keyr) * 8;                             // hi half chunk, u16 idx
    int chL = ((4 + g) ^ keyr) * 8;                       // lo half chunk

    f32x4 acc[MT][4] = {};

    for (int k0 = 0; k0 < 1024; k0 += 32) {
        // issue this K-tile's staging (direct-to-LDS DMA)
#pragma unroll
        for (int c = 0; c < AC; c++)
            gl16(gA + c * (8 * 2048) + k0, lA + c * (8 * 64));
#pragma unroll
        for (int c = 0; c < 4; c++)
            gl16(gB + c * (8 * 2048) + k0, lB + c * (8 * 64));
        __syncthreads();                                  // vmcnt drain: tile ready

        s16x8 bhf[4], blf[4];
#pragma unroll
        for (int nt = 0; nt < 4; nt++) {
            int br = (wn + nt * 16 + l15) * 64;
            bhf[nt] = *(const s16x8*)&BhL[br + chH];
            blf[nt] = *(const s16x8*)&BhL[br + chL];
        }
#pragma unroll
        for (int mt = 0; mt < MT; mt++) {
            int ar = (wm + mt * 16 + l15) * 64;
            s16x8 ah = *(const s16x8*)&AhL[ar + chH];
            s16x8 al = *(const s16x8*)&AhL[ar + chL];
#pragma unroll
            for (int nt = 0; nt < 4; nt++) {
                acc[mt][nt] = mfma16(ah, bhf[nt], acc[mt][nt]);
                acc[mt][nt] = mfma16(al, bhf[nt], acc[mt][nt]);
                acc[mt][nt] = mfma16(ah, blf[nt], acc[mt][nt]);
            }
        }
        __syncthreads();                                  // reads done before next overwrite
    }

    float bv4[4];
#pragma unroll
    for (int nt = 0; nt < 4; nt++)
        bv4[nt] = bias ? bias[bn + wn + nt * 16 + l15] : 0.0f;
    if (mode == 0) {
        u16* Co = Cb + (size_t)widx * (4096 * 1024);
#pragma unroll
        for (int mt = 0; mt < MT; mt++)
#pragma unroll
            for (int r = 0; r < 4; r++) {
                int row = bm + wm + mt * 16 + g * 4 + r;
                u16* cp = Co + (size_t)row * 1024 + bn + wn + l15;
#pragma unroll
                for (int nt = 0; nt < 4; nt++)
                    cp[16 * nt] = f2bf((acc[mt][nt][r] + bv4[nt]) * csc);
            }
    } else {
#pragma unroll
        for (int mt = 0; mt < MT; mt++)
#pragma unroll
            for (int r = 0; r < 4; r++) {
                int row = bm + wm + mt * 16 + g * 4 + r;
                float* cp = C + (size_t)row * 1024 + bn + wn + l15;
#pragma unroll
                for (int nt = 0; nt < 4; nt++)
                    cp[16 * nt] = acc[mt][nt][r] + bv4[nt];
            }
    }
}

// ---------------------------------------------------------------- V transpose to tiled [b][h][jt][d][32]
__global__ __launch_bounds__(256) void vtrans_kernel(const u16* __restrict__ v,
                                                     u16* __restrict__ vT) {
    __shared__ u16 L[32 * 72];
    int jt = blockIdx.x, h = blockIdx.y, b = blockIdx.z;
    int tid = threadIdx.x;
    int row = tid >> 3, cc = tid & 7;
    const u16* src = v + ((size_t)(b * Sx + jt * 32 + row)) * Dm + h * 64 + cc * 8;
    *(s16x8*)&L[row * 72 + cc * 8] = *(const s16x8*)src;
    __syncthreads();
    int d = tid >> 2, jq = tid & 3;
    s16x8 o;
#pragma unroll
    for (int jj = 0; jj < 8; jj++) o[jj] = (short)L[(jq * 8 + jj) * 72 + d];
    u16* dst = vT + (((size_t)(b * 16 + h) * 64 + jt)) * 2048 + d * 32 + jq * 8;
    *(s16x8*)dst = o;
}

// ---------------------------------------------------------------- precompute u.k_j and vb.p_r (bf16 in; k/p pre-scaled)
__global__ __launch_bounds__(256) void ukvb_kernel(const u16* __restrict__ k,
                                                   const u16* __restrict__ pp,
                                                   const float* __restrict__ u,
                                                   const float* __restrict__ vb,
                                                   float* __restrict__ ukg,
                                                   float* __restrict__ vbg) {
    int jid = blockIdx.x * 256 + threadIdx.x;
    const u16* src; const float* vec; float* dst; int idx;
    if (jid < 2 * Hh * Sx) {
        int j = jid & 2047, h = (jid >> 11) & 15, b = jid >> 15;
        src = k + ((size_t)(b * Sx + j)) * Dm + h * 64;
        vec = u + h * 64; dst = ukg; idx = jid;
    } else {
        int j2 = jid - 2 * Hh * Sx;
        int r = j2 & 2047, h = j2 >> 11;
        src = pp + (size_t)r * Dm + h * 64;
        vec = vb + h * 64; dst = vbg; idx = j2;
    }
    float s = 0.0f;
#pragma unroll
    for (int c = 0; c < 8; c++) {
        s16x8 kk = *(const s16x8*)(src + c * 8);
#pragma unroll
        for (int i = 0; i < 8; i++) s += bf2f((u16)kk[i]) * vec[c * 8 + i];
    }
    dst[idx] = s;
}

// ---------------------------------------------------------------- MFMA helpers for flash
__device__ __forceinline__ void wfill2(s16x8 a0, s16x8 a1, const u16* PW,
                                       int g, int l15, f32x4& d0, f32x4& d1) {
    f32x4 z = {0.f, 0.f, 0.f, 0.f};
    s16x8 b00 = *(const s16x8*)&PW[l15 * 72 + g * 8];
    s16x8 b01 = *(const s16x8*)&PW[l15 * 72 + 32 + g * 8];
    s16x8 b10 = *(const s16x8*)&PW[(16 + l15) * 72 + g * 8];
    s16x8 b11 = *(const s16x8*)&PW[(16 + l15) * 72 + 32 + g * 8];
    d0 = __builtin_amdgcn_mfma_f32_16x16x32_bf16(a0, b00, z, 0, 0, 0);
    d0 = __builtin_amdgcn_mfma_f32_16x16x32_bf16(a1, b01, d0, 0, 0, 0);
    d1 = __builtin_amdgcn_mfma_f32_16x16x32_bf16(a0, b10, z, 0, 0, 0);
    d1 = __builtin_amdgcn_mfma_f32_16x16x32_bf16(a1, b11, d1, 0, 0, 0);
}

// fill window chunk: skewed circular slots, physical = (logical_vr + row) % 96, stride 98
__device__ __forceinline__ void window_fill(s16x8 aq0, s16x8 aq1, s16x8 ab0, s16x8 ab1,
                                            const u16* PW, float* Ws,
                                            const float* __restrict__ vbb,
                                            int vstart, int sb, int rbase, int g, int l15) {
    f32x4 e0, e1;
    if (vstart + 31 <= Sx) {
        wfill2(aq0, aq1, PW, g, l15, e0, e1);
    } else if (vstart > Sx) {
        wfill2(ab0, ab1, PW, g, l15, e0, e1);
    } else {
        f32x4 d0, d1, f0, f1;
        wfill2(aq0, aq1, PW, g, l15, d0, d1);
        wfill2(ab0, ab1, PW, g, l15, f0, f1);
        int v0 = vstart + l15, v1 = vstart + 16 + l15;
#pragma unroll
        for (int r = 0; r < 4; r++) {
            e0[r] = (v0 > Sx) ? f0[r] : d0[r];
            e1[r] = (v1 > Sx) ? f1[r] : d1[r];
        }
    }
    int v0 = vstart + l15, v1 = vstart + 16 + l15;
    int pc0 = v0 < Sx ? v0 : v0 - Sx - 1;
    int pc1 = v1 < Sx ? v1 : v1 - Sx - 1;
    float vb0 = (v0 == Sx) ? 0.0f : vbb[pc0];
    float vb1 = (v1 == Sx) ? 0.0f : vbb[pc1];
    int bs = sb + rbase;
#pragma unroll
    for (int r = 0; r < 4; r++) {
        int b2 = bs + r; if (b2 >= 96) b2 -= 96;
        int sl0 = b2 + l15; if (sl0 >= 96) sl0 -= 96;
        int sl1 = sl0 + 16; if (sl1 >= 96) sl1 -= 96;
        Ws[(rbase + r) * 98 + sl0] = (v0 == Sx) ? 0.0f : e0[r] + vb0;
        Ws[(rbase + r) * 98 + sl1] = (v1 == Sx) ? 0.0f : e1[r] + vb1;
    }
}

// ---------------------------------------------------------------- flash attention (round-3, frozen)
__global__ __launch_bounds__(256, 4) void flash_kernel(const u16* __restrict__ q,
                                                       const u16* __restrict__ k,
                                                       const u16* __restrict__ vt,
                                                       const u16* __restrict__ pp,
                                                       const float* __restrict__ ukg,
                                                       const float* __restrict__ vbg,
                                                       u16* __restrict__ head16) {
    __shared__ __align__(16) unsigned char smem[39424];
    float* Ws = (float*)smem;                    // 64*98*4 = 25088 (live whole kernel)
    u16*   Qs = (u16*)smem;                      // 65*72*2 = 9360  (prologue only, aliased)
    u16*   Kt = (u16*)(smem + 25088);            // 32*72*2 = 4608
    u16*   PW = (u16*)(smem + 29696);            // 32*72*2 = 4608
    u16*   PA = (u16*)(smem + 34304);            // 64*40*2 = 5120

    int tid = threadIdx.x, blk = blockIdx.x;
    int grp = (blk & 7) + 8 * (blk >> 8);        // 0..31 = b*16 + h
    int it  = (blk >> 3) & 31;
    int h = grp & 15, b = grp >> 4;
    int i0 = it * 64;
    int a0 = 1984 - i0;

    const u16* qb  = q  + ((size_t)b * Sx) * Dm + h * 64;
    const u16* kb  = k  + ((size_t)b * Sx) * Dm + h * 64;
    const u16* vtb = vt + ((size_t)(b * 16 + h) * 64) * 2048;
    const u16* ppb = pp + h * 64;
    const float* ukb = ukg + (size_t)(b * Hh + h) * Sx;
    const float* vbb = vbg + (size_t)h * Sx;

    int w = tid >> 6, ln = tid & 63, g = ln >> 4, l15 = ln & 15;
    int rv = tid >> 3, ch = tid & 7;
    int rbase = 16 * w + 4 * g;

    for (int c = tid; c < 65 * 8; c += 256) {
        int row = c >> 3, cc = c & 7;
        int i = i0 + row;
        s16x8 tv = {0, 0, 0, 0, 0, 0, 0, 0};
        if (i < Sx) tv = *(const s16x8*)(qb + (size_t)i * Dm + cc * 8);
        *(s16x8*)&Qs[row * 72 + cc * 8] = tv;
    }
    __syncthreads();

    s16x8 aq0 = *(const s16x8*)&Qs[(16 * w + l15) * 72 + g * 8];
    s16x8 aq1 = *(const s16x8*)&Qs[(16 * w + l15) * 72 + 32 + g * 8];
    s16x8 ab0 = *(const s16x8*)&Qs[(16 * w + 1 + l15) * 72 + g * 8];
    s16x8 ab1 = *(const s16x8*)&Qs[(16 * w + 1 + l15) * 72 + 32 + g * 8];
    __syncthreads();     // all waves done reading Qs before any Ws write (aliased)

    for (int f = 0; f < 3; f++) {
        int vrb = f * 32;
        if (f) __syncthreads();
        {
            int vv = a0 + vrb + rv;
            s16x8 tv = {0, 0, 0, 0, 0, 0, 0, 0};
            if (vv != Sx) {
                int pc = vv < Sx ? vv : vv - Sx - 1;
                tv = *(const s16x8*)(ppb + (size_t)pc * Dm + ch * 8);
            }
            *(s16x8*)&PW[rv * 72 + ch * 8] = tv;
        }
        __syncthreads();
        window_fill(aq0, aq1, ab0, ab1, PW, Ws, vbb, a0 + vrb, vrb, rbase, g, l15);
    }

    f32x4 O[4] = {{0.f,0.f,0.f,0.f},{0.f,0.f,0.f,0.f},{0.f,0.f,0.f,0.f},{0.f,0.f,0.f,0.f}};
    float m_w = -1e30f;
    float l_i[4] = {0.f, 0.f, 0.f, 0.f};
    int wro[4];
#pragma unroll
    for (int r = 0; r < 4; r++) wro[r] = (rbase + r) * 98;
    int sb = 0;
    int jm = 63;
    int cw = (g >= 2) ? 16 : 0;
    int crd = (l15 >> 3) << 4;
    int pard = (16 * w + l15) * 40 + ((g * 8 + crd) & 31);

    const u16* pK = kb + (size_t)rv * Dm + ch * 8;
    const u16* pV = vtb + l15 * 32 + g * 8;
    s16x8 rK = *(const s16x8*)pK;
    s16x8 rPW = {0, 0, 0, 0, 0, 0, 0, 0};

    for (int t = 0; t < 64; t++) {
        int j0 = t * 32;
        __syncthreads();   // B0
        *(s16x8*)&Kt[rv * 72 + ch * 8] = rK;
        if (t >= 1) *(s16x8*)&PW[rv * 72 + ch * 8] = rPW;

        s16x8 bv0 = *(const s16x8*)(pV);
        s16x8 bv1 = *(const s16x8*)(pV + 512);
        s16x8 bv2 = *(const s16x8*)(pV + 1024);
        s16x8 bv3 = *(const s16x8*)(pV + 1536);
        pV += 2048;

        pK += 32 * Dm;
        rK = *(const s16x8*)pK;
        {
            int vv = a0 + (t + 3) * 32 + rv;
            s16x8 z8 = {0, 0, 0, 0, 0, 0, 0, 0};
            if (vv != Sx) {
                int pc = vv < Sx ? vv : vv - Sx - 1;
                if (pc > Sx - 1) pc = Sx - 1;
                z8 = *(const s16x8*)(ppb + (size_t)pc * Dm + ch * 8);
            }
            rPW = z8;
        }
        float uk0 = ukb[j0 + l15];
        float uk1 = ukb[j0 + 16 + l15];
        __syncthreads();   // B1

        f32x4 s0, s1;
        {
            f32x4 z = {0.f, 0.f, 0.f, 0.f};
            s16x8 bk00 = *(const s16x8*)&Kt[l15 * 72 + g * 8];
            s16x8 bk01 = *(const s16x8*)&Kt[l15 * 72 + 32 + g * 8];
            s16x8 bk10 = *(const s16x8*)&Kt[(16 + l15) * 72 + g * 8];
            s16x8 bk11 = *(const s16x8*)&Kt[(16 + l15) * 72 + 32 + g * 8];
            s0 = __builtin_amdgcn_mfma_f32_16x16x32_bf16(aq0, bk00, z, 0, 0, 0);
            s0 = __builtin_amdgcn_mfma_f32_16x16x32_bf16(aq1, bk01, s0, 0, 0, 0);
            s1 = __builtin_amdgcn_mfma_f32_16x16x32_bf16(aq0, bk10, z, 0, 0, 0);
            s1 = __builtin_amdgcn_mfma_f32_16x16x32_bf16(aq1, bk11, s1, 0, 0, 0);
        }

        if (t >= 1) {
            window_fill(aq0, aq1, ab0, ab1, PW, Ws, vbb, a0 + j0 + 64, sb, rbase, g, l15);
            sb += 32; if (sb >= 96) sb -= 96;
        }

        int si0 = jm + l15; if (si0 >= 96) si0 -= 96;
        int si1 = si0 + 16; if (si1 >= 96) si1 -= 96;
        jm += 32; if (jm >= 96) jm -= 96;
        float lg0[4], lg1[4];
#pragma unroll
        for (int r = 0; r < 4; r++) {
            lg0[r] = s0[r] + uk0 + Ws[wro[r] + si0];
            lg1[r] = s1[r] + uk1 + Ws[wro[r] + si1];
        }
        float pmax = fmaxf(fmaxf(fmaxf(lg0[0], lg1[0]), fmaxf(lg0[1], lg1[1])),
                           fmaxf(fmaxf(lg0[2], lg1[2]), fmaxf(lg0[3], lg1[3])));
        if (__any(pmax > m_w + 8.0f)) {
            float mx = pmax;
#pragma unroll
            for (int o = 1; o < 64; o <<= 1) mx = fmaxf(mx, __shfl_xor(mx, o, 64));
            float alpha = EXP2(m_w - mx);
            m_w = mx;
            l_i[0] *= alpha; l_i[1] *= alpha; l_i[2] *= alpha; l_i[3] *= alpha;
#pragma unroll
            for (int nt = 0; nt < 4; nt++)
#pragma unroll
                for (int r = 0; r < 4; r++) O[nt][r] *= alpha;
        }
        int c0 = l15 + cw;
        int c1 = l15 + 16 - cw;
#pragma unroll
        for (int r = 0; r < 4; r++) {
            float e0v = EXP2(lg0[r] - m_w);
            float e1v = EXP2(lg1[r] - m_w);
            l_i[r] += e0v + e1v;
#ifdef HAVE_PKBF16
            bfv2 pk2 = __builtin_amdgcn_cvt_pk_bf16_f32(e0v, e1v);
            PA[(rbase + r) * 40 + c0] = __builtin_bit_cast(u16, pk2[0]);
            PA[(rbase + r) * 40 + c1] = __builtin_bit_cast(u16, pk2[1]);
#else
            PA[(rbase + r) * 40 + c0] = f2bf(e0v);
            PA[(rbase + r) * 40 + c1] = f2bf(e1v);
#endif
        }

        {
            s16x8 ap = *(const s16x8*)&PA[pard];
            O[0] = __builtin_amdgcn_mfma_f32_16x16x32_bf16(ap, bv0, O[0], 0, 0, 0);
            O[1] = __builtin_amdgcn_mfma_f32_16x16x32_bf16(ap, bv1, O[1], 0, 0, 0);
            O[2] = __builtin_amdgcn_mfma_f32_16x16x32_bf16(ap, bv2, O[2], 0, 0, 0);
            O[3] = __builtin_amdgcn_mfma_f32_16x16x32_bf16(ap, bv3, O[3], 0, 0, 0);
        }
    }

#pragma unroll
    for (int r = 0; r < 4; r++) {
        float l = l_i[r];
#pragma unroll
        for (int o = 1; o < 16; o <<= 1) l += __shfl_xor(l, o, 64);
        float inv = 1.0f / l;
        int grow = i0 + rbase + r;
        u16* dst = head16 + (size_t)(b * Sx + grow) * 2048 + h * 64 + l15;
#pragma unroll
        for (int nt = 0; nt < 4; nt++) {
            float f = O[nt][r] * inv;
            u16 hh = f2bf(f);
            dst[16 * nt]        = hh;
            dst[1024 + 16 * nt] = f2bf(f - bf2f(hh));
        }
    }
}

// ---------------------------------------------------------------- launcher
extern "C" void kernel_launch(void* const* d_in, const int* in_sizes, int n_in,
                              void* d_out, int out_size, void* d_ws, size_t ws_size,
                              hipStream_t stream) {
    const float* x    = (const float*)d_in[0];
    const float* ln_g = (const float*)d_in[1];
    const float* ln_b = (const float*)d_in[2];
    const float* Wq   = (const float*)d_in[3];
    const float* bq   = (const float*)d_in[4];
    const float* Wk   = (const float*)d_in[5];
    const float* bk   = (const float*)d_in[6];
    const float* Wv   = (const float*)d_in[7];
    const float* bv   = (const float*)d_in[8];
    const float* Wp   = (const float*)d_in[9];
    const float* Wo   = (const float*)d_in[10];
    const float* bo   = (const float*)d_in[11];
    const float* ub   = (const float*)d_in[12];
    const float* vbias= (const float*)d_in[13];

    float* out = (float*)d_out;
    u16* base  = (u16*)d_ws;

    const int MROWS = 2 * Sx;                          // 4096
    u16* xn16   = base;                                // [4096][2048] hi|lo
    u16* head16 = base + 8u  * 1024 * 1024;            // [4096][2048] hi|lo
    u16* pe16   = base + 16u * 1024 * 1024;            // [2048][2048] hi|lo
    u16* qb16   = base + 20u * 1024 * 1024;            // [4096][1024]; k/v/p at +4M strides
    u16* kb16   = base + 24u * 1024 * 1024;
    u16* vb16   = base + 28u * 1024 * 1024;
    u16* pp16   = base + 32u * 1024 * 1024;            // [2048][1024]
    u16* vT16   = base + 34u * 1024 * 1024;            // [2][16][64][64][32]
    u16* WT     = base + 38u * 1024 * 1024;            // 5 x [1024][2048]
    float* ukg  = (float*)(base + 48u * 1024 * 1024);
    float* vbg  = ukg + 2 * Hh * Sx;

    ln_kernel<<<MROWS, 256, 0, stream>>>(x, ln_g, ln_b, xn16);
    pe_kernel<<<Sx * 512 / 256, 256, 0, stream>>>(pe16);

    dim3 gw(32, 32, 5);
    wconv_kernel<<<gw, 256, 0, stream>>>(Wq, Wk, Wv, Wp, Wo, WT);

    // fused Q/K/V/P projections: 768 QKV tiles + 128 pe tiles
    gemm128k<128><<<896, 256, 0, stream>>>(xn16, pe16, WT, bq, bk, bv, qb16, nullptr, 0);

    dim3 gv(Sx / 32, Hh, 2);
    vtrans_kernel<<<gv, 256, 0, stream>>>(vb16, vT16);

    ukvb_kernel<<<(2 * Hh * Sx + Hh * Sx) / 256, 256, 0, stream>>>(kb16, pp16, ub, vbias, ukg, vbg);

    flash_kernel<<<2 * Hh * 32, 256, 0, stream>>>(qb16, kb16, vT16, pp16, ukg, vbg, head16);

    gemm128k<64><<<dim3(8, 64), 256, 0, stream>>>(head16, nullptr, WT, bo, nullptr, nullptr, nullptr, out, 1);
}